// Round 1
// 1663.399 us; speedup vs baseline: 4.2944x; 4.2944x over previous
//
#include <hip/hip_runtime.h>

#define BB 4
#define LL 2048
#define DMODEL 2048
#define DSTATE 64
#define DCONV 4
#define DINNER 4096
#define NHEADS 64
#define CONVDIM 4224   // DINNER + 2*DSTATE
#define DINPROJ 8384   // 2*DINNER + 2*DSTATE + NHEADS
#define NPAD1   8448   // DINPROJ padded to multiple of 128 for MFMA tiles
#define MROWS 8192     // BB*LL
#define DTROW0 8320    // 2*DINNER + 2*DSTATE : first dt row of in_proj_w

typedef short bf16x8 __attribute__((ext_vector_type(8)));   // 8 bf16 (4 VGPRs)
typedef float f32x4  __attribute__((ext_vector_type(4)));   // MFMA accumulator
typedef __attribute__((address_space(1))) void as1_void;
typedef __attribute__((address_space(3))) void as3_void;

__device__ inline unsigned short f2bf(float f) {
  unsigned int u = __float_as_uint(f);
  u += 0x7FFF + ((u >> 16) & 1);   // RNE
  return (unsigned short)(u >> 16);
}
__device__ inline float bf2f(unsigned short u) {
  return __uint_as_float(((unsigned int)u) << 16);
}

// ---------------- fp32 -> bf16 conversion (float4 / ushort4 vectorized) ----------------
__global__ void f32_to_bf16_kernel(const float* __restrict__ in,
                                   unsigned short* __restrict__ out, long nquads) {
  long q = (long)blockIdx.x * 256 + threadIdx.x;
  if (q >= nquads) return;
  float4 v = ((const float4*)in)[q];
  ushort4 o;
  o.x = f2bf(v.x); o.y = f2bf(v.y); o.z = f2bf(v.z); o.w = f2bf(v.w);
  ((ushort4*)out)[q] = o;
}

// in_proj_w [8384][2048] fp32 -> bf16 padded to [8448][2048] (pad rows = 0)
__global__ void convert_w1_kernel(const float* __restrict__ w,
                                  unsigned short* __restrict__ out) {
  long q = (long)blockIdx.x * 256 + threadIdx.x;   // quad index over [8448][2048]
  long row = q >> 9;                               // 512 quads per row
  ushort4 o; o.x = 0; o.y = 0; o.z = 0; o.w = 0;
  if (row < DINPROJ) {
    float4 v = ((const float4*)w)[q];
    o.x = f2bf(v.x); o.y = f2bf(v.y); o.z = f2bf(v.z); o.w = f2bf(v.w);
  }
  ((ushort4*)out)[q] = o;
}

// ---------------- bf16 MFMA GEMM: C[M,N] = A[M,K] * B[N,K]^T ----------------
// m97 structure: 128x128 tile, BK=64, 4 waves (each owns 64x64 = 4x4 frags of
// 16x16x32 MFMA), global_load_lds width=16 staging, XOR-swizzled LDS
// (byte c ^= (row&7)<<4 within each 128B row) applied on BOTH sides:
// pre-swizzled GLOBAL source address + swizzled ds_read address (LDS write is
// linear, as global_load_lds requires). M % 128 == 0, K % 64 == 0,
// B has >= gridDim.x*128 rows (padded); C stores guarded by n < N.
template <bool BF16OUT>
__global__ __launch_bounds__(256) void gemm_mfma(
    const unsigned short* __restrict__ A,   // bf16 [M][K]
    const unsigned short* __restrict__ B,   // bf16 [Npad][K]
    void* __restrict__ Cv, int M, int N, int K) {
  __shared__ __align__(16) char sA[128 * 128];   // 128 rows x 64 bf16 (128B)
  __shared__ __align__(16) char sB[128 * 128];
  const int tid  = threadIdx.x;
  const int lane = tid & 63;
  const int wave = tid >> 6;
  const long m0 = (long)blockIdx.y * 128;
  const long n0 = (long)blockIdx.x * 128;
  const int wm = (wave >> 1) * 64;   // wave's 64x64 sub-tile
  const int wn = (wave & 1) * 64;
  const int fr = lane & 15;          // fragment row (A row / B col within 16)
  const int kb = lane >> 4;          // k-block 0..3 (x8 bf16 = x16 bytes)
  const int xr = (fr & 7) << 4;      // read-side XOR ((row&7)<<4; wm,i*16 are mult of 8)
  const size_t strideA = (size_t)K * 2;   // bytes per row (K mult of 64 -> 16B aligned)

  f32x4 acc[4][4] = {};   // zero-init accumulators (64 VGPRs)

  for (int k0 = 0; k0 < K; k0 += 64) {
    __syncthreads();   // all waves done reading previous tile
#pragma unroll
    for (int u = 0; u < 4; ++u) {
      const int idx  = u * 256 + tid;              // 16B slot 0..1023
      const int row  = idx >> 3;                   // 8 slots per 128B row
      const int csrc = ((idx & 7) << 4) ^ ((row & 7) << 4);  // pre-swizzled source col
      const char* ga = (const char*)A + (size_t)(m0 + row) * strideA + (size_t)k0 * 2 + csrc;
      const char* gb = (const char*)B + (size_t)(n0 + row) * strideA + (size_t)k0 * 2 + csrc;
      __builtin_amdgcn_global_load_lds((as1_void*)ga, (as3_void*)(sA + idx * 16), 16, 0, 0);
      __builtin_amdgcn_global_load_lds((as1_void*)gb, (as3_void*)(sB + idx * 16), 16, 0, 0);
    }
    __syncthreads();   // compiler drains vmcnt(0) before s_barrier -> tile visible
#pragma unroll
    for (int kh = 0; kh < 2; ++kh) {
      bf16x8 af[4], bg[4];
      const int cread = (kh * 64 + kb * 16) ^ xr;  // swizzled read col (bytes)
#pragma unroll
      for (int i = 0; i < 4; ++i) {
        const int ar = wm + i * 16 + fr;
        af[i] = *(const bf16x8*)(sA + ar * 128 + cread);
        const int br = wn + i * 16 + fr;
        bg[i] = *(const bf16x8*)(sB + br * 128 + cread);
      }
#pragma unroll
      for (int i = 0; i < 4; ++i)
#pragma unroll
        for (int j = 0; j < 4; ++j)
          acc[i][j] = __builtin_amdgcn_mfma_f32_16x16x32_bf16(af[i], bg[j], acc[i][j], 0, 0, 0);
    }
  }

  // epilogue: C/D layout col = lane&15, row = (lane>>4)*4 + reg  [verified m89/m91]
#pragma unroll
  for (int i = 0; i < 4; ++i) {
    const long mbase = m0 + wm + i * 16 + kb * 4;
#pragma unroll
    for (int j = 0; j < 4; ++j) {
      const long n = n0 + wn + j * 16 + fr;
      if (n < N) {
#pragma unroll
        for (int r = 0; r < 4; ++r) {
          const long m = mbase + r;
          if (BF16OUT) ((unsigned short*)Cv)[m * (long)N + n] = f2bf(acc[i][j][r]);
          else         ((float*)Cv)[m * (long)N + n] = acc[i][j][r];
        }
      }
    }
  }
}

// ---------------- fp32 dt path: dt_raw = x @ w_dt^T, softplus, dA ----------------
__global__ void dt_kernel(const float* __restrict__ x,
                          const float* __restrict__ w,     // in_proj_w (full)
                          const float* __restrict__ dt_bias,
                          const float* __restrict__ A_log,
                          float* __restrict__ dtv, float* __restrict__ dAv) {
  __shared__ float s_w[64][129];
  __shared__ float s_x[16][129];
  const int tid = threadIdx.x;
  const int row0 = blockIdx.x * 16;
  const int c = tid & 63;        // head
  const int rg = tid >> 6;       // 0..3 -> rows rg*4..rg*4+3
  float acc[4] = {0.f, 0.f, 0.f, 0.f};
  for (int k0 = 0; k0 < DMODEL; k0 += 128) {
    __syncthreads();
#pragma unroll
    for (int u = 0; u < 32; ++u) {   // 64*128/256
      int idx = u * 256 + tid;
      int r = idx >> 7, kk = idx & 127;
      s_w[r][kk] = w[(size_t)(DTROW0 + r) * DMODEL + k0 + kk];
    }
#pragma unroll
    for (int u = 0; u < 8; ++u) {    // 16*128/256
      int idx = u * 256 + tid;
      int r = idx >> 7, kk = idx & 127;
      s_x[r][kk] = x[(size_t)(row0 + r) * DMODEL + k0 + kk];
    }
    __syncthreads();
    for (int kk = 0; kk < 128; ++kk) {
      float wv = s_w[c][kk];
#pragma unroll
      for (int j = 0; j < 4; ++j) acc[j] += s_x[rg * 4 + j][kk] * wv;
    }
  }
  const float a = expf(A_log[c]);
  const float bias = dt_bias[c];
#pragma unroll
  for (int j = 0; j < 4; ++j) {
    int row = row0 + rg * 4 + j;
    float v = acc[j] + bias;
    float dt = (v > 20.f) ? v : log1pf(expf(v));   // softplus
    dtv[(size_t)row * 64 + c] = dt;
    dAv[(size_t)row * 64 + c] = expf(-dt * a);
  }
}

// ---------------- conv(4) + silu ----------------
__global__ void conv_kernel(const unsigned short* __restrict__ zxb,
                            const float* __restrict__ conv_w,
                            const float* __restrict__ conv_b,
                            unsigned short* __restrict__ xh,
                            float* __restrict__ Bm,
                            float* __restrict__ Cm) {
  const int row = blockIdx.x;          // b*LL + l
  const int l = row & (LL - 1);
  for (int c = threadIdx.x; c < CONVDIM; c += 256) {
    float acc = conv_b[c];
#pragma unroll
    for (int k = 0; k < DCONV; ++k) {
      int ll = l - (DCONV - 1) + k;
      if (ll >= 0) {
        size_t rr = (size_t)row + (ll - l);
        acc += bf2f(zxb[rr * DINPROJ + DINNER + c]) * conv_w[c * DCONV + k];
      }
    }
    float s = acc / (1.f + expf(-acc));   // silu
    if (c < DINNER)               xh[(size_t)row * DINNER + c] = f2bf(s);
    else if (c < DINNER + DSTATE) Bm[(size_t)row * DSTATE + (c - DINNER)] = s;
    else                          Cm[(size_t)row * DSTATE + (c - DINNER - DSTATE)] = s;
  }
}

// ---------------- sequential selective scan ----------------
#define CT 16
__global__ void scan_kernel(const unsigned short* xh,      // NOT restrict: y aliases xh
                            const float* __restrict__ Bm,
                            const float* __restrict__ Cm,
                            const float* __restrict__ dtv,
                            const float* __restrict__ dAv,
                            const float* __restrict__ Dv,
                            unsigned short* y) {
  __shared__ __align__(16) float s_x[CT][64];
  __shared__ __align__(16) float s_B[CT][64];
  __shared__ __align__(16) float s_C[CT][64];
  __shared__ __align__(16) float s_y[CT][64];
  __shared__ float s_dt[CT], s_dA[CT];
  const int b = blockIdx.x >> 6;
  const int head = blockIdx.x & 63;
  const int tid = threadIdx.x;
  const int p = tid >> 2, q = tid & 3, n0 = q * 16;
  const float Dh = Dv[head];
  float h[16];
#pragma unroll
  for (int i = 0; i < 16; ++i) h[i] = 0.f;

  for (int t0 = 0; t0 < LL; t0 += CT) {
    __syncthreads();   // previous chunk's s_y reads done before overwrite
#pragma unroll
    for (int u = 0; u < CT * 64 / 256; ++u) {
      int idx = u * 256 + tid;
      int tt = idx >> 6, cc = idx & 63;
      size_t r = (size_t)(b * LL + t0 + tt);
      s_x[tt][cc] = bf2f(xh[r * DINNER + head * 64 + cc]);
      s_B[tt][cc] = Bm[r * 64 + cc];
      s_C[tt][cc] = Cm[r * 64 + cc];
    }
    if (tid < CT) {
      size_t r = (size_t)(b * LL + t0 + tid);
      s_dt[tid] = dtv[r * 64 + head];
      s_dA[tid] = dAv[r * 64 + head];
    }
    __syncthreads();
    for (int tt = 0; tt < CT; ++tt) {
      float dA = s_dA[tt], dt = s_dt[tt];
      float xp = s_x[tt][p];
      float dtx = dt * xp;
      const float4* Bp = (const float4*)&s_B[tt][n0];
      const float4* Cp = (const float4*)&s_C[tt][n0];
      float ys = 0.f;
#pragma unroll
      for (int i = 0; i < 4; ++i) {
        float4 bv = Bp[i];
        float4 cv = Cp[i];
        h[4*i+0] = h[4*i+0] * dA + dtx * bv.x;  ys += h[4*i+0] * cv.x;
        h[4*i+1] = h[4*i+1] * dA + dtx * bv.y;  ys += h[4*i+1] * cv.y;
        h[4*i+2] = h[4*i+2] * dA + dtx * bv.z;  ys += h[4*i+2] * cv.z;
        h[4*i+3] = h[4*i+3] * dA + dtx * bv.w;  ys += h[4*i+3] * cv.w;
      }
      ys += __shfl_xor(ys, 1);
      ys += __shfl_xor(ys, 2);
      if (q == 0) s_y[tt][p] = ys + Dh * xp;
    }
    __syncthreads();   // all waves' s_y writes visible before cross-wave reads
#pragma unroll
    for (int u = 0; u < CT * 64 / 256; ++u) {
      int idx = u * 256 + tid;
      int tt = idx >> 6, cc = idx & 63;
      size_t r = (size_t)(b * LL + t0 + tt);
      y[r * DINNER + head * 64 + cc] = f2bf(s_y[tt][cc]);
    }
  }
}

// ---------------- gated RMSNorm (in-place bf16) ----------------
__global__ void norm_kernel(const unsigned short* y,       // NOT restrict: ynb aliases y
                            const unsigned short* __restrict__ zxb,
                            const float* __restrict__ norm_w,
                            unsigned short* ynb) {
  const int row = blockIdx.x;
  const int tid = threadIdx.x;
  float g[16];
  float ss = 0.f;
#pragma unroll
  for (int i = 0; i < 16; ++i) {
    int d = i * 256 + tid;
    float zv = bf2f(zxb[(size_t)row * DINPROJ + d]);
    float gv = bf2f(y[(size_t)row * DINNER + d]) * (zv / (1.f + expf(-zv)));
    g[i] = gv;
    ss += gv * gv;
  }
#pragma unroll
  for (int off = 32; off >= 1; off >>= 1) ss += __shfl_xor(ss, off);
  __shared__ float sred[4];
  __shared__ float s_rs;
  if ((tid & 63) == 0) sred[tid >> 6] = ss;
  __syncthreads();
  if (tid == 0) {
    float tot = sred[0] + sred[1] + sred[2] + sred[3];
    s_rs = rsqrtf(tot / (float)DINNER + 1e-5f);
  }
  __syncthreads();
  float rs = s_rs;
#pragma unroll
  for (int i = 0; i < 16; ++i) {
    int d = i * 256 + tid;
    ynb[(size_t)row * DINNER + d] = f2bf(g[i] * rs * norm_w[d]);
  }
}

// ---------------- classifier head (fp32 out — d_out is float32) ----------------
__global__ void cls_kernel(const float* __restrict__ h,
                           const float* __restrict__ cls_w,
                           const float* __restrict__ cls_b,
                           float* __restrict__ out) {
  const int row = blockIdx.x;
  const int tid = threadIdx.x;
  float a0 = 0, a1 = 0, a2 = 0, a3 = 0;
  for (int d = tid; d < DMODEL; d += 256) {
    float hv = h[(size_t)row * DMODEL + d];
    a0 += hv * cls_w[d];
    a1 += hv * cls_w[DMODEL + d];
    a2 += hv * cls_w[2 * DMODEL + d];
    a3 += hv * cls_w[3 * DMODEL + d];
  }
#pragma unroll
  for (int off = 32; off >= 1; off >>= 1) {
    a0 += __shfl_xor(a0, off); a1 += __shfl_xor(a1, off);
    a2 += __shfl_xor(a2, off); a3 += __shfl_xor(a3, off);
  }
  __shared__ float sred[4][4];
  if ((tid & 63) == 0) { int w = tid >> 6; sred[w][0] = a0; sred[w][1] = a1; sred[w][2] = a2; sred[w][3] = a3; }
  __syncthreads();
  if (tid < 4) {
    float s = sred[0][tid] + sred[1][tid] + sred[2][tid] + sred[3][tid] + cls_b[tid];
    out[(size_t)row * 4 + tid] = s;   // fp32 store: reference output dtype is float32
  }
}

extern "C" void kernel_launch(void* const* d_in, const int* in_sizes, int n_in,
                              void* d_out, int out_size, void* d_ws, size_t ws_size,
                              hipStream_t stream) {
  const float* x          = (const float*)d_in[0];
  const float* in_proj_w  = (const float*)d_in[1];
  const float* conv_w     = (const float*)d_in[2];
  const float* conv_b     = (const float*)d_in[3];
  const float* dt_bias    = (const float*)d_in[4];
  const float* A_log      = (const float*)d_in[5];
  const float* Dv         = (const float*)d_in[6];
  const float* norm_w     = (const float*)d_in[7];
  const float* out_proj_w = (const float*)d_in[8];
  const float* cls_w      = (const float*)d_in[9];
  const float* cls_b      = (const float*)d_in[10];

  char* ws = (char*)d_ws;
  // workspace layout (total 212,860,928 bytes — unchanged from previous session):
  unsigned short* zxb = (unsigned short*)(ws + 0);            // 137,363,456  bf16 [8192,8384]
  unsigned short* xh  = (unsigned short*)(ws + 137363456);    //  67,108,864  bf16 [8192,4096]
  float*          Bmp = (float*)(ws + 204472320);             //   2,097,152
  float*          Cmp = (float*)(ws + 206569472);             //   2,097,152
  float*          dtv = (float*)(ws + 208666624);             //   2,097,152
  float*          dAv = (float*)(ws + 210763776);             //   2,097,152  -> end 212,860,928
  // stream-ordered aliases (regions dead at reuse time):
  unsigned short* ynb  = xh;                       // in-place over y (elementwise)
  float*          hbuf = (float*)zxb;              // fp32 [8192,2048] over zxb (dead after norm)
  // bf16 GEMM operand staging (dead-region aliases):
  unsigned short* xbf = xh;                                        // [8192,2048] bf16, 33.5 MB (xh live only after conv)
  unsigned short* w1b = (unsigned short*)((char*)xh + 33554432);   // [8448,2048] bf16, 34.6 MB (spills 1 MB into Bmp region — Bmp written later by conv)
  unsigned short* w2b = (unsigned short*)((char*)zxb + 67108864);  // [2048,4096] bf16, 16.8 MB (zxb dead after norm; hbuf uses first 67 MB only)

  // 0. bf16 operand conversion for gemm1 (into regions not yet live)
  f32_to_bf16_kernel<<<16384, 256, 0, stream>>>(x, xbf, 4194304);          // 8192*2048/4
  convert_w1_kernel<<<16896, 256, 0, stream>>>(in_proj_w, w1b);            // 8448*512 quads

  // 1. fp32 dt path (independent of gemm1; reads fp32 x and in_proj_w directly)
  dt_kernel<<<512, 256, 0, stream>>>(x, in_proj_w, dt_bias, A_log, dtv, dAv);

  // 2. in-projection GEMM (bf16 MFMA): zxb[8192,8384] = x @ in_proj_w^T
  gemm_mfma<true><<<dim3(NPAD1 / 128, MROWS / 128), 256, 0, stream>>>(
      xbf, w1b, zxb, MROWS, DINPROJ, DMODEL);

  // 3. conv + silu (overwrites xbf/w1b — dead after gemm1)
  conv_kernel<<<MROWS, 256, 0, stream>>>(zxb, conv_w, conv_b, xh, Bmp, Cmp);

  // 4. selective scan (y in-place over xh)
  scan_kernel<<<256, 256, 0, stream>>>(xh, Bmp, Cmp, dtv, dAv, Dv, xh);

  // 5. gated RMSNorm (in-place bf16 over y)
  norm_kernel<<<MROWS, 256, 0, stream>>>(xh, zxb, norm_w, ynb);

  // 5b. bf16 conversion of out_proj_w (zxb region dead after norm)
  f32_to_bf16_kernel<<<8192, 256, 0, stream>>>(out_proj_w, w2b, 2097152);  // 2048*4096/4

  // 6. out-projection GEMM (bf16 MFMA): hbuf[8192,2048] = ynb @ out_proj_w^T (fp32 out)
  gemm_mfma<false><<<dim3(DMODEL / 128, MROWS / 128), 256, 0, stream>>>(
      ynb, w2b, hbuf, MROWS, DMODEL, DINNER);

  // 7. classifier -> fp32 out
  cls_kernel<<<MROWS, 256, 0, stream>>>(hbuf, cls_w, cls_b, (float*)d_out);
}

// Round 2
// 1568.176 us; speedup vs baseline: 4.5551x; 1.0607x over previous
//
#include <hip/hip_runtime.h>

#define BB 4
#define LL 2048
#define DMODEL 2048
#define DSTATE 64
#define DCONV 4
#define DINNER 4096
#define NHEADS 64
#define CONVDIM 4224   // DINNER + 2*DSTATE
#define DINPROJ 8384   // 2*DINNER + 2*DSTATE + NHEADS
#define NPAD1   8448   // DINPROJ padded to multiple of 128 for MFMA tiles
#define MROWS 8192     // BB*LL
#define DTROW0 8320    // 2*DINNER + 2*DSTATE : first dt row of in_proj_w
#define XBCCOLS 4288   // CONVDIM + NHEADS (cols 4096..8383 of zxbcdt)

typedef short bf16x8 __attribute__((ext_vector_type(8)));   // 8 bf16 (4 VGPRs)
typedef float f32x4  __attribute__((ext_vector_type(4)));   // MFMA accumulator
typedef __attribute__((address_space(1))) void as1_void;
typedef __attribute__((address_space(3))) void as3_void;

__device__ inline unsigned short f2bf(float f) {
  unsigned int u = __float_as_uint(f);
  u += 0x7FFF + ((u >> 16) & 1);   // RNE
  return (unsigned short)(u >> 16);
}
__device__ inline float bf2f(unsigned short u) {
  return __uint_as_float(((unsigned int)u) << 16);
}

// ---------------- fp32 -> bf16 conversion (float4 / ushort4 vectorized) ----------------
__global__ void f32_to_bf16_kernel(const float* __restrict__ in,
                                   unsigned short* __restrict__ out, long nquads) {
  long q = (long)blockIdx.x * 256 + threadIdx.x;
  if (q >= nquads) return;
  float4 v = ((const float4*)in)[q];
  ushort4 o;
  o.x = f2bf(v.x); o.y = f2bf(v.y); o.z = f2bf(v.z); o.w = f2bf(v.w);
  ((ushort4*)out)[q] = o;
}

// in_proj_w [8384][2048] fp32 -> bf16 padded to [8448][2048] (pad rows = 0)
__global__ void convert_w1_kernel(const float* __restrict__ w,
                                  unsigned short* __restrict__ out) {
  long q = (long)blockIdx.x * 256 + threadIdx.x;   // quad index over [8448][2048]
  long row = q >> 9;                               // 512 quads per row
  ushort4 o; o.x = 0; o.y = 0; o.z = 0; o.w = 0;
  if (row < DINPROJ) {
    float4 v = ((const float4*)w)[q];
    o.x = f2bf(v.x); o.y = f2bf(v.y); o.z = f2bf(v.z); o.w = f2bf(v.w);
  }
  ((ushort4*)out)[q] = o;
}

// ---------------- bf16 MFMA GEMM: C[M,N] = A[M,K] * B[N,K]^T ----------------
// m97 structure: 128x128 tile, BK=64, 4 waves (each owns 64x64 = 4x4 frags of
// 16x16x32 MFMA), global_load_lds width=16 staging, XOR-swizzled LDS
// (byte c ^= (row&7)<<4) applied BOTH-sides: pre-swizzled global source addr +
// swizzled ds_read addr (LDS write linear, as global_load_lds requires).
// M % 128 == 0, K % 64 == 0, B padded to gridDim.x*128 rows; C stores guarded.
// SPLIT: col n < Nsplit -> Cv (ld=Nsplit), else Cv2 (ld=ld2, col n-Nsplit).
template <bool BF16OUT, bool SPLIT>
__global__ __launch_bounds__(256) void gemm_mfma(
    const unsigned short* __restrict__ A,   // bf16 [M][K]
    const unsigned short* __restrict__ B,   // bf16 [Npad][K]
    void* __restrict__ Cv, void* __restrict__ Cv2,
    int M, int N, int K, int Nsplit, int ld2) {
  __shared__ __align__(16) char sA[128 * 128];   // 128 rows x 64 bf16 (128B)
  __shared__ __align__(16) char sB[128 * 128];
  const int tid  = threadIdx.x;
  const int lane = tid & 63;
  const int wave = tid >> 6;
  const long m0 = (long)blockIdx.y * 128;
  const long n0 = (long)blockIdx.x * 128;
  const int wm = (wave >> 1) * 64;   // wave's 64x64 sub-tile
  const int wn = (wave & 1) * 64;
  const int fr = lane & 15;          // fragment row (A row / B col within 16)
  const int kb = lane >> 4;          // k-block 0..3 (x8 bf16 = x16 bytes)
  const int xr = (fr & 7) << 4;      // read-side XOR ((row&7)<<4)
  const size_t strideA = (size_t)K * 2;   // bytes per row

  f32x4 acc[4][4] = {};

  for (int k0 = 0; k0 < K; k0 += 64) {
    __syncthreads();   // all waves done reading previous tile
#pragma unroll
    for (int u = 0; u < 4; ++u) {
      const int idx  = u * 256 + tid;              // 16B slot 0..1023
      const int row  = idx >> 3;                   // 8 slots per 128B row
      const int csrc = ((idx & 7) << 4) ^ ((row & 7) << 4);  // pre-swizzled source col
      const char* ga = (const char*)A + (size_t)(m0 + row) * strideA + (size_t)k0 * 2 + csrc;
      const char* gb = (const char*)B + (size_t)(n0 + row) * strideA + (size_t)k0 * 2 + csrc;
      __builtin_amdgcn_global_load_lds((as1_void*)ga, (as3_void*)(sA + idx * 16), 16, 0, 0);
      __builtin_amdgcn_global_load_lds((as1_void*)gb, (as3_void*)(sB + idx * 16), 16, 0, 0);
    }
    __syncthreads();   // vmcnt(0) drained before barrier -> tile visible
#pragma unroll
    for (int kh = 0; kh < 2; ++kh) {
      bf16x8 af[4], bg[4];
      const int cread = (kh * 64 + kb * 16) ^ xr;  // swizzled read col (bytes)
#pragma unroll
      for (int i = 0; i < 4; ++i) {
        const int ar = wm + i * 16 + fr;
        af[i] = *(const bf16x8*)(sA + ar * 128 + cread);
        const int br = wn + i * 16 + fr;
        bg[i] = *(const bf16x8*)(sB + br * 128 + cread);
      }
#pragma unroll
      for (int i = 0; i < 4; ++i)
#pragma unroll
        for (int j = 0; j < 4; ++j)
          acc[i][j] = __builtin_amdgcn_mfma_f32_16x16x32_bf16(af[i], bg[j], acc[i][j], 0, 0, 0);
    }
  }

  // epilogue: C/D layout col = lane&15, row = (lane>>4)*4 + reg  [verified m89/m91]
#pragma unroll
  for (int i = 0; i < 4; ++i) {
    const long mbase = m0 + wm + i * 16 + kb * 4;
#pragma unroll
    for (int j = 0; j < 4; ++j) {
      const long n = n0 + wn + j * 16 + fr;
      if (n < N) {
#pragma unroll
        for (int r = 0; r < 4; ++r) {
          const long m = mbase + r;
          if (!SPLIT || n < Nsplit) {
            const long ld = SPLIT ? Nsplit : N;
            if (BF16OUT) ((unsigned short*)Cv)[m * ld + n] = f2bf(acc[i][j][r]);
            else         ((float*)Cv)[m * ld + n] = acc[i][j][r];
          } else {
            if (BF16OUT) ((unsigned short*)Cv2)[m * (long)ld2 + (n - Nsplit)] = f2bf(acc[i][j][r]);
            else         ((float*)Cv2)[m * (long)ld2 + (n - Nsplit)] = acc[i][j][r];
          }
        }
      }
    }
  }
}

// ---------------- fp32 dt path: dt_raw = x @ w_dt^T, softplus, dA ----------------
__global__ void dt_kernel(const float* __restrict__ x,
                          const float* __restrict__ w,     // in_proj_w (full)
                          const float* __restrict__ dt_bias,
                          const float* __restrict__ A_log,
                          float* __restrict__ dtv, float* __restrict__ dAv) {
  __shared__ float s_w[64][129];
  __shared__ float s_x[16][129];
  const int tid = threadIdx.x;
  const int row0 = blockIdx.x * 16;
  const int c = tid & 63;        // head
  const int rg = tid >> 6;       // 0..3 -> rows rg*4..rg*4+3
  float acc[4] = {0.f, 0.f, 0.f, 0.f};
  for (int k0 = 0; k0 < DMODEL; k0 += 128) {
    __syncthreads();
#pragma unroll
    for (int u = 0; u < 32; ++u) {   // 64*128/256
      int idx = u * 256 + tid;
      int r = idx >> 7, kk = idx & 127;
      s_w[r][kk] = w[(size_t)(DTROW0 + r) * DMODEL + k0 + kk];
    }
#pragma unroll
    for (int u = 0; u < 8; ++u) {    // 16*128/256
      int idx = u * 256 + tid;
      int r = idx >> 7, kk = idx & 127;
      s_x[r][kk] = x[(size_t)(row0 + r) * DMODEL + k0 + kk];
    }
    __syncthreads();
    for (int kk = 0; kk < 128; ++kk) {
      float wv = s_w[c][kk];
#pragma unroll
      for (int j = 0; j < 4; ++j) acc[j] += s_x[rg * 4 + j][kk] * wv;
    }
  }
  const float a = expf(A_log[c]);
  const float bias = dt_bias[c];
#pragma unroll
  for (int j = 0; j < 4; ++j) {
    int row = row0 + rg * 4 + j;
    float v = acc[j] + bias;
    float dt = (v > 20.f) ? v : log1pf(expf(v));   // softplus
    dtv[(size_t)row * 64 + c] = dt;
    dAv[(size_t)row * 64 + c] = expf(-dt * a);
  }
}

// ---------------- conv(4) + silu (reads xbc buffer [8192][4288]) ----------------
__global__ void conv_kernel(const unsigned short* __restrict__ xbc,
                            const float* __restrict__ conv_w,
                            const float* __restrict__ conv_b,
                            unsigned short* __restrict__ xh,
                            float* __restrict__ Bm,
                            float* __restrict__ Cm) {
  const int row = blockIdx.x;          // b*LL + l
  const int l = row & (LL - 1);
  for (int c = threadIdx.x; c < CONVDIM; c += 256) {
    float acc = conv_b[c];
#pragma unroll
    for (int k = 0; k < DCONV; ++k) {
      int ll = l - (DCONV - 1) + k;
      if (ll >= 0) {
        size_t rr = (size_t)row + (ll - l);
        acc += bf2f(xbc[rr * XBCCOLS + c]) * conv_w[c * DCONV + k];
      }
    }
    float s = acc / (1.f + expf(-acc));   // silu
    if (c < DINNER)               xh[(size_t)row * DINNER + c] = f2bf(s);
    else if (c < DINNER + DSTATE) Bm[(size_t)row * DSTATE + (c - DINNER)] = s;
    else                          Cm[(size_t)row * DSTATE + (c - DINNER - DSTATE)] = s;
  }
}

// ---------------- chunked selective scan ----------------
// h_t = dA_t*h_{t-1} + dt_t*x_t (x) B_t  is linear in h, so per 128-step chunk:
// h_end = (prod dA)*h_start + h_local_end.  Pass A1 computes h_local_end per
// chunk in parallel (4096 blocks, full occupancy); pass B serially combines
// chunk boundaries (trivial); pass A2 re-runs each chunk from its true h_start
// producing y — identical FMA sequence to the monolithic scan.
#define CT 16
#define CHUNK 128
#define NCHUNK 16   // LL / CHUNK

// Pass A1: per-(b,h,chunk) local state scan from h=0 -> hend + chunk decay prod.
__global__ void scan_state_kernel(const unsigned short* __restrict__ xhp,
                                  const float* __restrict__ Bm,
                                  const float* __restrict__ dtv,
                                  const float* __restrict__ dAv,
                                  float* __restrict__ hend,
                                  float* __restrict__ chunkA) {
  __shared__ __align__(16) float s_x[CT][64];
  __shared__ __align__(16) float s_B[CT][64];
  __shared__ float s_dt[CT], s_dA[CT];
  const int chunk = blockIdx.x & (NCHUNK - 1);
  const int bh = blockIdx.x >> 4;
  const int head = bh & 63;
  const int b = bh >> 6;
  const int tid = threadIdx.x;
  const int p = tid >> 2, q = tid & 3, n0 = q * 16;
  float h[16];
#pragma unroll
  for (int i = 0; i < 16; ++i) h[i] = 0.f;
  float pA = 1.f;
  const int tbase = b * LL + chunk * CHUNK;

  for (int t0 = 0; t0 < CHUNK; t0 += CT) {
    __syncthreads();
#pragma unroll
    for (int u = 0; u < CT * 64 / 256; ++u) {
      int idx = u * 256 + tid;
      int tt = idx >> 6, cc = idx & 63;
      size_t r = (size_t)(tbase + t0 + tt);
      s_x[tt][cc] = bf2f(xhp[r * DINNER + head * 64 + cc]);
      s_B[tt][cc] = Bm[r * 64 + cc];
    }
    if (tid < CT) {
      size_t r = (size_t)(tbase + t0 + tid);
      s_dt[tid] = dtv[r * 64 + head];
      s_dA[tid] = dAv[r * 64 + head];
    }
    __syncthreads();
    for (int tt = 0; tt < CT; ++tt) {
      float dA = s_dA[tt];
      float dtx = s_dt[tt] * s_x[tt][p];
      pA *= dA;
      const float4* Bp = (const float4*)&s_B[tt][n0];
#pragma unroll
      for (int i = 0; i < 4; ++i) {
        float4 bv = Bp[i];
        h[4*i+0] = h[4*i+0] * dA + dtx * bv.x;
        h[4*i+1] = h[4*i+1] * dA + dtx * bv.y;
        h[4*i+2] = h[4*i+2] * dA + dtx * bv.z;
        h[4*i+3] = h[4*i+3] * dA + dtx * bv.w;
      }
    }
  }
  // thread tid owns hend elements [tid*16 .. tid*16+15] (p*64 + q*16 == tid*16)
  float* hp = hend + ((size_t)bh * NCHUNK + chunk) * 4096 + tid * 16;
#pragma unroll
  for (int i = 0; i < 4; ++i) {
    float4 v; v.x = h[4*i]; v.y = h[4*i+1]; v.z = h[4*i+2]; v.w = h[4*i+3];
    ((float4*)hp)[i] = v;
  }
  if (tid == 0) chunkA[bh * NCHUNK + chunk] = pA;
}

// Pass B: in-place inter-chunk propagation: slot c := h_start(chunk c).
__global__ void scan_prop_kernel(float* __restrict__ hend,
                                 const float* __restrict__ chunkA) {
  const int bh = blockIdx.x;     // 256
  const int tid = threadIdx.x;   // 256
  float cr[16];
#pragma unroll
  for (int i = 0; i < 16; ++i) cr[i] = 0.f;
  for (int c = 0; c < NCHUNK; ++c) {
    float* hp = hend + ((size_t)bh * NCHUNK + c) * 4096 + tid * 16;
    const float a = chunkA[bh * NCHUNK + c];
    float e[16];
#pragma unroll
    for (int i = 0; i < 4; ++i) {
      float4 v = ((float4*)hp)[i];
      e[4*i] = v.x; e[4*i+1] = v.y; e[4*i+2] = v.z; e[4*i+3] = v.w;
    }
#pragma unroll
    for (int i = 0; i < 4; ++i) {
      float4 v; v.x = cr[4*i]; v.y = cr[4*i+1]; v.z = cr[4*i+2]; v.w = cr[4*i+3];
      ((float4*)hp)[i] = v;
    }
#pragma unroll
    for (int i = 0; i < 16; ++i) cr[i] = cr[i] * a + e[i];
  }
}

// Pass A2: full scan per chunk from h_start, writing y (in-place over xh).
__global__ void scan_apply_kernel(const unsigned short* xhp,   // NOT restrict: y aliases
                                  const float* __restrict__ Bm,
                                  const float* __restrict__ Cm,
                                  const float* __restrict__ dtv,
                                  const float* __restrict__ dAv,
                                  const float* __restrict__ Dv,
                                  const float* __restrict__ hstart,
                                  unsigned short* y) {
  __shared__ __align__(16) float s_x[CT][64];
  __shared__ __align__(16) float s_B[CT][64];
  __shared__ __align__(16) float s_C[CT][64];
  __shared__ __align__(16) float s_y[CT][64];
  __shared__ float s_dt[CT], s_dA[CT];
  const int chunk = blockIdx.x & (NCHUNK - 1);
  const int bh = blockIdx.x >> 4;
  const int head = bh & 63;
  const int b = bh >> 6;
  const int tid = threadIdx.x;
  const int p = tid >> 2, q = tid & 3, n0 = q * 16;
  const float Dh = Dv[head];
  const int tbase = b * LL + chunk * CHUNK;

  float h[16];
  {
    const float* hp = hstart + ((size_t)bh * NCHUNK + chunk) * 4096 + tid * 16;
#pragma unroll
    for (int i = 0; i < 4; ++i) {
      float4 v = ((const float4*)hp)[i];
      h[4*i] = v.x; h[4*i+1] = v.y; h[4*i+2] = v.z; h[4*i+3] = v.w;
    }
  }

  for (int t0 = 0; t0 < CHUNK; t0 += CT) {
    __syncthreads();   // previous sub-chunk's s_y reads done before overwrite
#pragma unroll
    for (int u = 0; u < CT * 64 / 256; ++u) {
      int idx = u * 256 + tid;
      int tt = idx >> 6, cc = idx & 63;
      size_t r = (size_t)(tbase + t0 + tt);
      s_x[tt][cc] = bf2f(xhp[r * DINNER + head * 64 + cc]);
      s_B[tt][cc] = Bm[r * 64 + cc];
      s_C[tt][cc] = Cm[r * 64 + cc];
    }
    if (tid < CT) {
      size_t r = (size_t)(tbase + t0 + tid);
      s_dt[tid] = dtv[r * 64 + head];
      s_dA[tid] = dAv[r * 64 + head];
    }
    __syncthreads();
    for (int tt = 0; tt < CT; ++tt) {
      float dA = s_dA[tt], dt = s_dt[tt];
      float xp = s_x[tt][p];
      float dtx = dt * xp;
      const float4* Bp = (const float4*)&s_B[tt][n0];
      const float4* Cp = (const float4*)&s_C[tt][n0];
      float ys = 0.f;
#pragma unroll
      for (int i = 0; i < 4; ++i) {
        float4 bv = Bp[i];
        float4 cv = Cp[i];
        h[4*i+0] = h[4*i+0] * dA + dtx * bv.x;  ys += h[4*i+0] * cv.x;
        h[4*i+1] = h[4*i+1] * dA + dtx * bv.y;  ys += h[4*i+1] * cv.y;
        h[4*i+2] = h[4*i+2] * dA + dtx * bv.z;  ys += h[4*i+2] * cv.z;
        h[4*i+3] = h[4*i+3] * dA + dtx * bv.w;  ys += h[4*i+3] * cv.w;
      }
      ys += __shfl_xor(ys, 1);
      ys += __shfl_xor(ys, 2);
      if (q == 0) s_y[tt][p] = ys + Dh * xp;
    }
    __syncthreads();   // all waves' s_y writes visible before cross-wave reads
#pragma unroll
    for (int u = 0; u < CT * 64 / 256; ++u) {
      int idx = u * 256 + tid;
      int tt = idx >> 6, cc = idx & 63;
      size_t r = (size_t)(tbase + t0 + tt);
      y[r * DINNER + head * 64 + cc] = f2bf(s_y[tt][cc]);
    }
  }
}

// ---------------- gated RMSNorm (in-place bf16; z from zbuf) ----------------
__global__ void norm_kernel(const unsigned short* y,       // NOT restrict: ynb aliases y
                            const unsigned short* __restrict__ zbuf,
                            const float* __restrict__ norm_w,
                            unsigned short* ynb) {
  const int row = blockIdx.x;
  const int tid = threadIdx.x;
  float g[16];
  float ss = 0.f;
#pragma unroll
  for (int i = 0; i < 16; ++i) {
    int d = i * 256 + tid;
    float zv = bf2f(zbuf[(size_t)row * DINNER + d]);
    float gv = bf2f(y[(size_t)row * DINNER + d]) * (zv / (1.f + expf(-zv)));
    g[i] = gv;
    ss += gv * gv;
  }
#pragma unroll
  for (int off = 32; off >= 1; off >>= 1) ss += __shfl_xor(ss, off);
  __shared__ float sred[4];
  __shared__ float s_rs;
  if ((tid & 63) == 0) sred[tid >> 6] = ss;
  __syncthreads();
  if (tid == 0) {
    float tot = sred[0] + sred[1] + sred[2] + sred[3];
    s_rs = rsqrtf(tot / (float)DINNER + 1e-5f);
  }
  __syncthreads();
  float rs = s_rs;
#pragma unroll
  for (int i = 0; i < 16; ++i) {
    int d = i * 256 + tid;
    ynb[(size_t)row * DINNER + d] = f2bf(g[i] * rs * norm_w[d]);
  }
}

// ---------------- classifier head (fp32 out — d_out is float32) ----------------
__global__ void cls_kernel(const float* __restrict__ h,
                           const float* __restrict__ cls_w,
                           const float* __restrict__ cls_b,
                           float* __restrict__ out) {
  const int row = blockIdx.x;
  const int tid = threadIdx.x;
  float a0 = 0, a1 = 0, a2 = 0, a3 = 0;
  for (int d = tid; d < DMODEL; d += 256) {
    float hv = h[(size_t)row * DMODEL + d];
    a0 += hv * cls_w[d];
    a1 += hv * cls_w[DMODEL + d];
    a2 += hv * cls_w[2 * DMODEL + d];
    a3 += hv * cls_w[3 * DMODEL + d];
  }
#pragma unroll
  for (int off = 32; off >= 1; off >>= 1) {
    a0 += __shfl_xor(a0, off); a1 += __shfl_xor(a1, off);
    a2 += __shfl_xor(a2, off); a3 += __shfl_xor(a3, off);
  }
  __shared__ float sred[4][4];
  if ((tid & 63) == 0) { int w = tid >> 6; sred[w][0] = a0; sred[w][1] = a1; sred[w][2] = a2; sred[w][3] = a3; }
  __syncthreads();
  if (tid < 4) {
    float s = sred[0][tid] + sred[1][tid] + sred[2][tid] + sred[3][tid] + cls_b[tid];
    out[(size_t)row * 4 + tid] = s;
  }
}

extern "C" void kernel_launch(void* const* d_in, const int* in_sizes, int n_in,
                              void* d_out, int out_size, void* d_ws, size_t ws_size,
                              hipStream_t stream) {
  const float* x          = (const float*)d_in[0];
  const float* in_proj_w  = (const float*)d_in[1];
  const float* conv_w     = (const float*)d_in[2];
  const float* conv_b     = (const float*)d_in[3];
  const float* dt_bias    = (const float*)d_in[4];
  const float* A_log      = (const float*)d_in[5];
  const float* Dv         = (const float*)d_in[6];
  const float* norm_w     = (const float*)d_in[7];
  const float* out_proj_w = (const float*)d_in[8];
  const float* cls_w      = (const float*)d_in[9];
  const float* cls_b      = (const float*)d_in[10];

  char* ws = (char*)d_ws;
  // workspace layout (total 212,860,928 bytes — same size as before, zxb split):
  unsigned short* zbuf = (unsigned short*)(ws + 0);           //  67,108,864  bf16 [8192,4096]  z cols
  unsigned short* xbc  = (unsigned short*)(ws + 67108864);    //  70,254,592  bf16 [8192,4288]  xBC+dt cols
  unsigned short* xh   = (unsigned short*)(ws + 137363456);   //  67,108,864  bf16 [8192,4096]
  float*          Bmp  = (float*)(ws + 204472320);            //   2,097,152
  float*          Cmp  = (float*)(ws + 206569472);            //   2,097,152
  float*          dtv  = (float*)(ws + 208666624);            //   2,097,152
  float*          dAv  = (float*)(ws + 210763776);            //   2,097,152  -> end 212,860,928
  // stream-ordered aliases (regions dead at reuse time):
  unsigned short* ynb  = xh;                       // in-place over y (elementwise)
  float*          hbuf = (float*)zbuf;             // fp32 [8192,2048] (zbuf dead after norm)
  // bf16 GEMM operand staging for gemm1 (xh region live only after conv):
  unsigned short* xbf = xh;                                        // [8192,2048] bf16, 33.5 MB
  unsigned short* w1b = (unsigned short*)((char*)xh + 33554432);   // [8448,2048] bf16, 34.6 MB (1MB spill into Bmp — written later by conv)
  // scan chunk-state buffers (xbc region dead after conv):
  float*          hend   = (float*)xbc;                            // [256][16][4096] f32 = 67 MB
  float*          chunkA = (float*)((char*)xbc + 67108864);        // [4096] f32 (xbc tail)
  // gemm2 weight staging (xbc region dead after scan passes):
  unsigned short* w2b = (unsigned short*)xbc;                      // [2048,4096] bf16, 16.8 MB

  // 0. bf16 operand conversion for gemm1
  f32_to_bf16_kernel<<<16384, 256, 0, stream>>>(x, xbf, 4194304);          // 8192*2048/4
  convert_w1_kernel<<<16896, 256, 0, stream>>>(in_proj_w, w1b);            // 8448*512 quads

  // 1. fp32 dt path (reads fp32 x and in_proj_w directly)
  dt_kernel<<<512, 256, 0, stream>>>(x, in_proj_w, dt_bias, A_log, dtv, dAv);

  // 2. in-projection GEMM (bf16 MFMA), split output: z -> zbuf, xBC+dt -> xbc
  gemm_mfma<true, true><<<dim3(NPAD1 / 128, MROWS / 128), 256, 0, stream>>>(
      xbf, w1b, zbuf, xbc, MROWS, DINPROJ, DMODEL, DINNER, XBCCOLS);

  // 3. conv + silu (overwrites xbf/w1b — dead after gemm1)
  conv_kernel<<<MROWS, 256, 0, stream>>>(xbc, conv_w, conv_b, xh, Bmp, Cmp);

  // 4. chunked selective scan (y in-place over xh; hend in dead xbc region)
  scan_state_kernel<<<256 * NCHUNK, 256, 0, stream>>>(xh, Bmp, dtv, dAv, hend, chunkA);
  scan_prop_kernel<<<256, 256, 0, stream>>>(hend, chunkA);
  scan_apply_kernel<<<256 * NCHUNK, 256, 0, stream>>>(xh, Bmp, Cmp, dtv, dAv, Dv, hend, xh);

  // 5. gated RMSNorm (in-place bf16 over y; z from zbuf)
  norm_kernel<<<MROWS, 256, 0, stream>>>(xh, zbuf, norm_w, ynb);

  // 5b. bf16 conversion of out_proj_w (xbc region dead after scan)
  f32_to_bf16_kernel<<<8192, 256, 0, stream>>>(out_proj_w, w2b, 2097152);  // 2048*4096/4

  // 6. out-projection GEMM (bf16 MFMA): hbuf[8192,2048] = ynb @ out_proj_w^T (fp32 out)
  gemm_mfma<false, false><<<dim3(DMODEL / 128, MROWS / 128), 256, 0, stream>>>(
      ynb, w2b, hbuf, nullptr, MROWS, DMODEL, DINNER, DMODEL, 0);

  // 7. classifier -> fp32 out
  cls_kernel<<<MROWS, 256, 0, stream>>>(hbuf, cls_w, cls_b, (float*)d_out);
}

// Round 3
// 1548.465 us; speedup vs baseline: 4.6131x; 1.0127x over previous
//
#include <hip/hip_runtime.h>

#define BB 4
#define LL 2048
#define DMODEL 2048
#define DSTATE 64
#define DCONV 4
#define DINNER 4096
#define NHEADS 64
#define CONVDIM 4224   // DINNER + 2*DSTATE
#define DINPROJ 8384   // 2*DINNER + 2*DSTATE + NHEADS
#define NPAD1   8448   // DINPROJ padded to multiple of 128 for MFMA tiles
#define MROWS 8192     // BB*LL
#define DTROW0 8320    // 2*DINNER + 2*DSTATE : first dt row of in_proj_w
#define XBCCOLS 4288   // CONVDIM + NHEADS (cols 4096..8383 of zxbcdt)

typedef short bf16x8 __attribute__((ext_vector_type(8)));   // 8 bf16 (4 VGPRs)
typedef short bf16x4 __attribute__((ext_vector_type(4)));   // 4 bf16 (2 VGPRs)
typedef float f32x4  __attribute__((ext_vector_type(4)));   // MFMA accumulator
typedef __attribute__((address_space(1))) void as1_void;
typedef __attribute__((address_space(3))) void as3_void;

__device__ inline unsigned short f2bf(float f) {
  unsigned int u = __float_as_uint(f);
  u += 0x7FFF + ((u >> 16) & 1);   // RNE
  return (unsigned short)(u >> 16);
}
__device__ inline float bf2f(unsigned short u) {
  return __uint_as_float(((unsigned int)u) << 16);
}

// ---------------- fp32 -> bf16 conversion (float4 / ushort4 vectorized) ----------------
__global__ void f32_to_bf16_kernel(const float* __restrict__ in,
                                   unsigned short* __restrict__ out, long nquads) {
  long q = (long)blockIdx.x * 256 + threadIdx.x;
  if (q >= nquads) return;
  float4 v = ((const float4*)in)[q];
  ushort4 o;
  o.x = f2bf(v.x); o.y = f2bf(v.y); o.z = f2bf(v.z); o.w = f2bf(v.w);
  ((ushort4*)out)[q] = o;
}

// in_proj_w [8384][2048] fp32 -> bf16 padded to [8448][2048] (pad rows = 0)
__global__ void convert_w1_kernel(const float* __restrict__ w,
                                  unsigned short* __restrict__ out) {
  long q = (long)blockIdx.x * 256 + threadIdx.x;   // quad index over [8448][2048]
  long row = q >> 9;                               // 512 quads per row
  ushort4 o; o.x = 0; o.y = 0; o.z = 0; o.w = 0;
  if (row < DINPROJ) {
    float4 v = ((const float4*)w)[q];
    o.x = f2bf(v.x); o.y = f2bf(v.y); o.z = f2bf(v.z); o.w = f2bf(v.w);
  }
  ((ushort4*)out)[q] = o;
}

// ---------------- bf16 MFMA GEMM: C[M,N] = A[M,K] * B[N,K]^T ----------------
// m97 structure + XCD-aware bijective block swizzle (nwg % 8 == 0 required for
// the simple form; guarded). 128x128 tile, BK=64, 4 waves, global_load_lds
// width=16, XOR-swizzle (byte c ^= (row&7)<<4) both-sides. M%128==0, K%64==0,
// B padded to gridDim.x*128 rows; C stores guarded by n < N.
// SPLIT: col n < Nsplit -> Cv (ld=Nsplit), else Cv2 (ld=ld2, col n-Nsplit).
template <bool BF16OUT, bool SPLIT>
__global__ __launch_bounds__(256) void gemm_mfma(
    const unsigned short* __restrict__ A,   // bf16 [M][K]
    const unsigned short* __restrict__ B,   // bf16 [Npad][K]
    void* __restrict__ Cv, void* __restrict__ Cv2,
    int M, int N, int K, int Nsplit, int ld2) {
  __shared__ __align__(16) char sA[128 * 128];   // 128 rows x 64 bf16 (128B)
  __shared__ __align__(16) char sB[128 * 128];
  const int tid  = threadIdx.x;
  const int lane = tid & 63;
  const int wave = tid >> 6;
  // XCD-aware swizzle: 8 XCDs get contiguous chunks of the linear grid (T1).
  const int nwg = gridDim.x * gridDim.y;
  int lin = blockIdx.y * gridDim.x + blockIdx.x;
  if ((nwg & 7) == 0) {
    const int q = nwg >> 3;
    lin = (lin & 7) * q + (lin >> 3);
  }
  const long m0 = (long)(lin / gridDim.x) * 128;
  const long n0 = (long)(lin % gridDim.x) * 128;
  const int wm = (wave >> 1) * 64;   // wave's 64x64 sub-tile
  const int wn = (wave & 1) * 64;
  const int fr = lane & 15;          // fragment row (A row / B col within 16)
  const int kb = lane >> 4;          // k-block 0..3 (x8 bf16 = x16 bytes)
  const int xr = (fr & 7) << 4;      // read-side XOR ((row&7)<<4)
  const size_t strideA = (size_t)K * 2;   // bytes per row

  f32x4 acc[4][4] = {};

  for (int k0 = 0; k0 < K; k0 += 64) {
    __syncthreads();   // all waves done reading previous tile
#pragma unroll
    for (int u = 0; u < 4; ++u) {
      const int idx  = u * 256 + tid;              // 16B slot 0..1023
      const int row  = idx >> 3;                   // 8 slots per 128B row
      const int csrc = ((idx & 7) << 4) ^ ((row & 7) << 4);  // pre-swizzled source col
      const char* ga = (const char*)A + (size_t)(m0 + row) * strideA + (size_t)k0 * 2 + csrc;
      const char* gb = (const char*)B + (size_t)(n0 + row) * strideA + (size_t)k0 * 2 + csrc;
      __builtin_amdgcn_global_load_lds((as1_void*)ga, (as3_void*)(sA + idx * 16), 16, 0, 0);
      __builtin_amdgcn_global_load_lds((as1_void*)gb, (as3_void*)(sB + idx * 16), 16, 0, 0);
    }
    __syncthreads();   // vmcnt(0) drained before barrier -> tile visible
#pragma unroll
    for (int kh = 0; kh < 2; ++kh) {
      bf16x8 af[4], bg[4];
      const int cread = (kh * 64 + kb * 16) ^ xr;  // swizzled read col (bytes)
#pragma unroll
      for (int i = 0; i < 4; ++i) {
        const int ar = wm + i * 16 + fr;
        af[i] = *(const bf16x8*)(sA + ar * 128 + cread);
        const int br = wn + i * 16 + fr;
        bg[i] = *(const bf16x8*)(sB + br * 128 + cread);
      }
#pragma unroll
      for (int i = 0; i < 4; ++i)
#pragma unroll
        for (int j = 0; j < 4; ++j)
          acc[i][j] = __builtin_amdgcn_mfma_f32_16x16x32_bf16(af[i], bg[j], acc[i][j], 0, 0, 0);
    }
  }

  // epilogue: C/D layout col = lane&15, row = (lane>>4)*4 + reg  [verified m89/m91]
#pragma unroll
  for (int i = 0; i < 4; ++i) {
    const long mbase = m0 + wm + i * 16 + kb * 4;
#pragma unroll
    for (int j = 0; j < 4; ++j) {
      const long n = n0 + wn + j * 16 + fr;
      if (n < N) {
#pragma unroll
        for (int r = 0; r < 4; ++r) {
          const long m = mbase + r;
          if (!SPLIT || n < Nsplit) {
            const long ld = SPLIT ? Nsplit : N;
            if (BF16OUT) ((unsigned short*)Cv)[m * ld + n] = f2bf(acc[i][j][r]);
            else         ((float*)Cv)[m * ld + n] = acc[i][j][r];
          } else {
            if (BF16OUT) ((unsigned short*)Cv2)[m * (long)ld2 + (n - Nsplit)] = f2bf(acc[i][j][r]);
            else         ((float*)Cv2)[m * (long)ld2 + (n - Nsplit)] = acc[i][j][r];
          }
        }
      }
    }
  }
}

// ---------------- fp32 dt path: dt_raw = x @ w_dt^T, softplus, dA ----------------
__global__ void dt_kernel(const float* __restrict__ x,
                          const float* __restrict__ w,     // in_proj_w (full)
                          const float* __restrict__ dt_bias,
                          const float* __restrict__ A_log,
                          float* __restrict__ dtv, float* __restrict__ dAv) {
  __shared__ float s_w[64][129];
  __shared__ float s_x[16][129];
  const int tid = threadIdx.x;
  const int row0 = blockIdx.x * 16;
  const int c = tid & 63;        // head
  const int rg = tid >> 6;       // 0..3 -> rows rg*4..rg*4+3
  float acc[4] = {0.f, 0.f, 0.f, 0.f};
  for (int k0 = 0; k0 < DMODEL; k0 += 128) {
    __syncthreads();
#pragma unroll
    for (int u = 0; u < 32; ++u) {   // 64*128/256
      int idx = u * 256 + tid;
      int r = idx >> 7, kk = idx & 127;
      s_w[r][kk] = w[(size_t)(DTROW0 + r) * DMODEL + k0 + kk];
    }
#pragma unroll
    for (int u = 0; u < 8; ++u) {    // 16*128/256
      int idx = u * 256 + tid;
      int r = idx >> 7, kk = idx & 127;
      s_x[r][kk] = x[(size_t)(row0 + r) * DMODEL + k0 + kk];
    }
    __syncthreads();
    for (int kk = 0; kk < 128; ++kk) {
      float wv = s_w[c][kk];
#pragma unroll
      for (int j = 0; j < 4; ++j) acc[j] += s_x[rg * 4 + j][kk] * wv;
    }
  }
  const float a = expf(A_log[c]);
  const float bias = dt_bias[c];
#pragma unroll
  for (int j = 0; j < 4; ++j) {
    int row = row0 + rg * 4 + j;
    float v = acc[j] + bias;
    float dt = (v > 20.f) ? v : log1pf(expf(v));   // softplus
    dtv[(size_t)row * 64 + c] = dt;
    dAv[(size_t)row * 64 + c] = expf(-dt * a);
  }
}

// ---------------- conv(4) + silu, vectorized (short8 per group) ----------------
// 528 groups of 8 channels; thread t handles groups {t, t+256, 512+t if t<16}.
__global__ void conv_kernel(const unsigned short* __restrict__ xbc,
                            const float* __restrict__ conv_w,
                            const float* __restrict__ conv_b,
                            unsigned short* __restrict__ xh,
                            float* __restrict__ Bm,
                            float* __restrict__ Cm) {
  const int row = blockIdx.x;          // b*LL + l
  const int l = row & (LL - 1);
  const int tid = threadIdx.x;
  for (int gsel = 0; gsel < 3; ++gsel) {
    int g;
    if (gsel == 0) g = tid;
    else if (gsel == 1) g = tid + 256;
    else { if (tid >= 16) break; g = 512 + tid; }
    const int c0 = g * 8;
    float cwa[8][4];
#pragma unroll
    for (int i = 0; i < 8; ++i) {
      float4 cw = *(const float4*)&conv_w[(c0 + i) * 4];
      cwa[i][0] = cw.x; cwa[i][1] = cw.y; cwa[i][2] = cw.z; cwa[i][3] = cw.w;
    }
    float acc[8];
    {
      float4 cb0 = *(const float4*)&conv_b[c0];
      float4 cb1 = *(const float4*)&conv_b[c0 + 4];
      acc[0] = cb0.x; acc[1] = cb0.y; acc[2] = cb0.z; acc[3] = cb0.w;
      acc[4] = cb1.x; acc[5] = cb1.y; acc[6] = cb1.z; acc[7] = cb1.w;
    }
#pragma unroll
    for (int k = 0; k < DCONV; ++k) {
      const int ll = l - (DCONV - 1) + k;
      if (ll >= 0) {   // wave-uniform (l uniform per block)
        const size_t rr = (size_t)(row - (DCONV - 1) + k);
        bf16x8 v = *(const bf16x8*)&xbc[rr * XBCCOLS + c0];
#pragma unroll
        for (int i = 0; i < 8; ++i)
          acc[i] += bf2f((unsigned short)v[i]) * cwa[i][k];
      }
    }
    float s[8];
#pragma unroll
    for (int i = 0; i < 8; ++i) s[i] = acc[i] / (1.f + expf(-acc[i]));
    if (g < 512) {
      bf16x8 o;
#pragma unroll
      for (int i = 0; i < 8; ++i) o[i] = (short)f2bf(s[i]);
      *(bf16x8*)&xh[(size_t)row * DINNER + c0] = o;
    } else {
      float4 o0, o1;
      o0.x = s[0]; o0.y = s[1]; o0.z = s[2]; o0.w = s[3];
      o1.x = s[4]; o1.y = s[5]; o1.z = s[6]; o1.w = s[7];
      if (g < 520) {
        float* p = &Bm[(size_t)row * DSTATE + (c0 - DINNER)];
        ((float4*)p)[0] = o0; ((float4*)p)[1] = o1;
      } else {
        float* p = &Cm[(size_t)row * DSTATE + (c0 - DINNER - DSTATE)];
        ((float4*)p)[0] = o0; ((float4*)p)[1] = o1;
      }
    }
  }
}

// ---------------- chunked selective scan ----------------
#define CT 16
#define CHUNK 128
#define NCHUNK 16   // LL / CHUNK

// Pass A1: per-(b,h,chunk) local state scan from h=0 -> hend + chunk decay prod.
__global__ void scan_state_kernel(const unsigned short* __restrict__ xhp,
                                  const float* __restrict__ Bm,
                                  const float* __restrict__ dtv,
                                  const float* __restrict__ dAv,
                                  float* __restrict__ hend,
                                  float* __restrict__ chunkA) {
  __shared__ __align__(16) float s_x[CT][64];
  __shared__ __align__(16) float s_B[CT][64];
  __shared__ float s_dt[CT], s_dA[CT];
  const int chunk = blockIdx.x & (NCHUNK - 1);
  const int bh = blockIdx.x >> 4;
  const int head = bh & 63;
  const int b = bh >> 6;
  const int tid = threadIdx.x;
  const int p = tid >> 2, q = tid & 3, n0 = q * 16;
  const int stt = tid >> 4, scc = (tid & 15) * 4;   // vectorized staging coords
  float h[16];
#pragma unroll
  for (int i = 0; i < 16; ++i) h[i] = 0.f;
  float pA = 1.f;
  const int tbase = b * LL + chunk * CHUNK;

  for (int t0 = 0; t0 < CHUNK; t0 += CT) {
    __syncthreads();
    {
      size_t r = (size_t)(tbase + t0 + stt);
      bf16x4 xv = *(const bf16x4*)&xhp[r * DINNER + head * 64 + scc];
      float4 xf;
      xf.x = bf2f((unsigned short)xv[0]); xf.y = bf2f((unsigned short)xv[1]);
      xf.z = bf2f((unsigned short)xv[2]); xf.w = bf2f((unsigned short)xv[3]);
      *(float4*)&s_x[stt][scc] = xf;
      *(float4*)&s_B[stt][scc] = *(const float4*)&Bm[r * 64 + scc];
    }
    if (tid < CT) {
      size_t r = (size_t)(tbase + t0 + tid);
      s_dt[tid] = dtv[r * 64 + head];
      s_dA[tid] = dAv[r * 64 + head];
    }
    __syncthreads();
    for (int tt = 0; tt < CT; ++tt) {
      float dA = s_dA[tt];
      float dtx = s_dt[tt] * s_x[tt][p];
      pA *= dA;
      const float4* Bp = (const float4*)&s_B[tt][n0];
#pragma unroll
      for (int i = 0; i < 4; ++i) {
        float4 bv = Bp[i];
        h[4*i+0] = h[4*i+0] * dA + dtx * bv.x;
        h[4*i+1] = h[4*i+1] * dA + dtx * bv.y;
        h[4*i+2] = h[4*i+2] * dA + dtx * bv.z;
        h[4*i+3] = h[4*i+3] * dA + dtx * bv.w;
      }
    }
  }
  float* hp = hend + ((size_t)bh * NCHUNK + chunk) * 4096 + tid * 16;
#pragma unroll
  for (int i = 0; i < 4; ++i) {
    float4 v; v.x = h[4*i]; v.y = h[4*i+1]; v.z = h[4*i+2]; v.w = h[4*i+3];
    ((float4*)hp)[i] = v;
  }
  if (tid == 0) chunkA[bh * NCHUNK + chunk] = pA;
}

// Pass B: in-place inter-chunk propagation: slot c := h_start(chunk c).
__global__ void scan_prop_kernel(float* __restrict__ hend,
                                 const float* __restrict__ chunkA) {
  const int bh = blockIdx.x;     // 256
  const int tid = threadIdx.x;   // 256
  float cr[16];
#pragma unroll
  for (int i = 0; i < 16; ++i) cr[i] = 0.f;
  for (int c = 0; c < NCHUNK; ++c) {
    float* hp = hend + ((size_t)bh * NCHUNK + c) * 4096 + tid * 16;
    const float a = chunkA[bh * NCHUNK + c];
    float e[16];
#pragma unroll
    for (int i = 0; i < 4; ++i) {
      float4 v = ((float4*)hp)[i];
      e[4*i] = v.x; e[4*i+1] = v.y; e[4*i+2] = v.z; e[4*i+3] = v.w;
    }
#pragma unroll
    for (int i = 0; i < 4; ++i) {
      float4 v; v.x = cr[4*i]; v.y = cr[4*i+1]; v.z = cr[4*i+2]; v.w = cr[4*i+3];
      ((float4*)hp)[i] = v;
    }
#pragma unroll
    for (int i = 0; i < 16; ++i) cr[i] = cr[i] * a + e[i];
  }
}

// Pass A2: full scan per chunk from h_start, writing y (in-place over xh).
__global__ void scan_apply_kernel(const unsigned short* xhp,   // NOT restrict: y aliases
                                  const float* __restrict__ Bm,
                                  const float* __restrict__ Cm,
                                  const float* __restrict__ dtv,
                                  const float* __restrict__ dAv,
                                  const float* __restrict__ Dv,
                                  const float* __restrict__ hstart,
                                  unsigned short* y) {
  __shared__ __align__(16) float s_x[CT][64];
  __shared__ __align__(16) float s_B[CT][64];
  __shared__ __align__(16) float s_C[CT][64];
  __shared__ __align__(16) float s_y[CT][64];
  __shared__ float s_dt[CT], s_dA[CT];
  const int chunk = blockIdx.x & (NCHUNK - 1);
  const int bh = blockIdx.x >> 4;
  const int head = bh & 63;
  const int b = bh >> 6;
  const int tid = threadIdx.x;
  const int p = tid >> 2, q = tid & 3, n0 = q * 16;
  const int stt = tid >> 4, scc = (tid & 15) * 4;
  const float Dh = Dv[head];
  const int tbase = b * LL + chunk * CHUNK;

  float h[16];
  {
    const float* hp = hstart + ((size_t)bh * NCHUNK + chunk) * 4096 + tid * 16;
#pragma unroll
    for (int i = 0; i < 4; ++i) {
      float4 v = ((const float4*)hp)[i];
      h[4*i] = v.x; h[4*i+1] = v.y; h[4*i+2] = v.z; h[4*i+3] = v.w;
    }
  }

  for (int t0 = 0; t0 < CHUNK; t0 += CT) {
    __syncthreads();   // previous sub-chunk's s_y reads done before overwrite
    {
      size_t r = (size_t)(tbase + t0 + stt);
      bf16x4 xv = *(const bf16x4*)&xhp[r * DINNER + head * 64 + scc];
      float4 xf;
      xf.x = bf2f((unsigned short)xv[0]); xf.y = bf2f((unsigned short)xv[1]);
      xf.z = bf2f((unsigned short)xv[2]); xf.w = bf2f((unsigned short)xv[3]);
      *(float4*)&s_x[stt][scc] = xf;
      *(float4*)&s_B[stt][scc] = *(const float4*)&Bm[r * 64 + scc];
      *(float4*)&s_C[stt][scc] = *(const float4*)&Cm[r * 64 + scc];
    }
    if (tid < CT) {
      size_t r = (size_t)(tbase + t0 + tid);
      s_dt[tid] = dtv[r * 64 + head];
      s_dA[tid] = dAv[r * 64 + head];
    }
    __syncthreads();
    for (int tt = 0; tt < CT; ++tt) {
      float dA = s_dA[tt], dt = s_dt[tt];
      float xp = s_x[tt][p];
      float dtx = dt * xp;
      const float4* Bp = (const float4*)&s_B[tt][n0];
      const float4* Cp = (const float4*)&s_C[tt][n0];
      float ys = 0.f;
#pragma unroll
      for (int i = 0; i < 4; ++i) {
        float4 bv = Bp[i];
        float4 cv = Cp[i];
        h[4*i+0] = h[4*i+0] * dA + dtx * bv.x;  ys += h[4*i+0] * cv.x;
        h[4*i+1] = h[4*i+1] * dA + dtx * bv.y;  ys += h[4*i+1] * cv.y;
        h[4*i+2] = h[4*i+2] * dA + dtx * bv.z;  ys += h[4*i+2] * cv.z;
        h[4*i+3] = h[4*i+3] * dA + dtx * bv.w;  ys += h[4*i+3] * cv.w;
      }
      ys += __shfl_xor(ys, 1);
      ys += __shfl_xor(ys, 2);
      if (q == 0) s_y[tt][p] = ys + Dh * xp;
    }
    __syncthreads();   // all waves' s_y writes visible before cross-wave reads
    {
      size_t r = (size_t)(tbase + t0 + stt);
      float4 yv = *(const float4*)&s_y[stt][scc];
      bf16x4 o;
      o[0] = (short)f2bf(yv.x); o[1] = (short)f2bf(yv.y);
      o[2] = (short)f2bf(yv.z); o[3] = (short)f2bf(yv.w);
      *(bf16x4*)&y[r * DINNER + head * 64 + scc] = o;
    }
  }
}

// ---------------- Wc = cls_w @ out_proj_w : [4][4096] fp32 ----------------
__global__ void wc_kernel(const float* __restrict__ W,    // out_proj_w [2048][4096]
                          const float* __restrict__ C,    // cls_w [4][2048]
                          float* __restrict__ Wc) {       // [4][4096]
  const int e = blockIdx.x * 256 + threadIdx.x;
  float a0 = 0, a1 = 0, a2 = 0, a3 = 0;
  for (int d = 0; d < DMODEL; ++d) {
    float wv = W[(size_t)d * DINNER + e];
    a0 += C[d] * wv;
    a1 += C[DMODEL + d] * wv;
    a2 += C[2 * DMODEL + d] * wv;
    a3 += C[3 * DMODEL + d] * wv;
  }
  Wc[e] = a0; Wc[DINNER + e] = a1; Wc[2 * DINNER + e] = a2; Wc[3 * DINNER + e] = a3;
}

// ---------------- fused gated RMSNorm + classifier projection ----------------
// out[row][c] = sum_d ( y*silu(z)*rs*norm_w )[d] * Wc[c][d] + cls_b[c]
__global__ void normcls_kernel(const unsigned short* __restrict__ y,
                               const unsigned short* __restrict__ z,
                               const float* __restrict__ norm_w,
                               const float* __restrict__ Wc,
                               const float* __restrict__ cls_b,
                               float* __restrict__ out) {
  const int row = blockIdx.x;
  const int tid = threadIdx.x;
  const int d0 = tid * 16;
  const size_t base = (size_t)row * DINNER + d0;
  bf16x8 yv0 = *(const bf16x8*)&y[base];
  bf16x8 yv1 = *(const bf16x8*)&y[base + 8];
  bf16x8 zv0 = *(const bf16x8*)&z[base];
  bf16x8 zv1 = *(const bf16x8*)&z[base + 8];
  float g[16];
  float ss = 0.f;
#pragma unroll
  for (int i = 0; i < 8; ++i) {
    float zz = bf2f((unsigned short)zv0[i]);
    float gv = bf2f((unsigned short)yv0[i]) * (zz / (1.f + expf(-zz)));
    g[i] = gv; ss += gv * gv;
  }
#pragma unroll
  for (int i = 0; i < 8; ++i) {
    float zz = bf2f((unsigned short)zv1[i]);
    float gv = bf2f((unsigned short)yv1[i]) * (zz / (1.f + expf(-zz)));
    g[8 + i] = gv; ss += gv * gv;
  }
#pragma unroll
  for (int off = 32; off >= 1; off >>= 1) ss += __shfl_xor(ss, off);
  __shared__ float sred[4];
  __shared__ float s_rs;
  if ((tid & 63) == 0) sred[tid >> 6] = ss;
  __syncthreads();
  if (tid == 0)
    s_rs = rsqrtf((sred[0] + sred[1] + sred[2] + sred[3]) / (float)DINNER + 1e-5f);
  __syncthreads();
  const float rs = s_rs;
  float gn[16];
#pragma unroll
  for (int j = 0; j < 4; ++j) {
    float4 nw = *(const float4*)&norm_w[d0 + j * 4];
    gn[j*4+0] = g[j*4+0] * rs * nw.x;
    gn[j*4+1] = g[j*4+1] * rs * nw.y;
    gn[j*4+2] = g[j*4+2] * rs * nw.z;
    gn[j*4+3] = g[j*4+3] * rs * nw.w;
  }
  float a[4] = {0.f, 0.f, 0.f, 0.f};
#pragma unroll
  for (int c = 0; c < 4; ++c) {
#pragma unroll
    for (int j = 0; j < 4; ++j) {
      float4 w4 = *(const float4*)&Wc[c * DINNER + d0 + j * 4];
      a[c] += gn[j*4+0]*w4.x + gn[j*4+1]*w4.y + gn[j*4+2]*w4.z + gn[j*4+3]*w4.w;
    }
  }
#pragma unroll
  for (int off = 32; off >= 1; off >>= 1) {
#pragma unroll
    for (int c = 0; c < 4; ++c) a[c] += __shfl_xor(a[c], off);
  }
  __shared__ float s4[4][4];
  if ((tid & 63) == 0) {
    int w = tid >> 6;
    s4[w][0] = a[0]; s4[w][1] = a[1]; s4[w][2] = a[2]; s4[w][3] = a[3];
  }
  __syncthreads();
  if (tid < 4)
    out[(size_t)row * 4 + tid] = s4[0][tid] + s4[1][tid] + s4[2][tid] + s4[3][tid] + cls_b[tid];
}

extern "C" void kernel_launch(void* const* d_in, const int* in_sizes, int n_in,
                              void* d_out, int out_size, void* d_ws, size_t ws_size,
                              hipStream_t stream) {
  const float* x          = (const float*)d_in[0];
  const float* in_proj_w  = (const float*)d_in[1];
  const float* conv_w     = (const float*)d_in[2];
  const float* conv_b     = (const float*)d_in[3];
  const float* dt_bias    = (const float*)d_in[4];
  const float* A_log      = (const float*)d_in[5];
  const float* Dv         = (const float*)d_in[6];
  const float* norm_w     = (const float*)d_in[7];
  const float* out_proj_w = (const float*)d_in[8];
  const float* cls_w      = (const float*)d_in[9];
  const float* cls_b      = (const float*)d_in[10];

  char* ws = (char*)d_ws;
  // workspace layout (total 212,860,928 bytes):
  unsigned short* zbuf = (unsigned short*)(ws + 0);           //  67,108,864  bf16 [8192,4096]  z cols
  unsigned short* xbc  = (unsigned short*)(ws + 67108864);    //  70,254,592  bf16 [8192,4288]  xBC+dt cols
  unsigned short* xh   = (unsigned short*)(ws + 137363456);   //  67,108,864  bf16 [8192,4096]
  float*          Bmp  = (float*)(ws + 204472320);            //   2,097,152
  float*          Cmp  = (float*)(ws + 206569472);            //   2,097,152
  float*          dtv  = (float*)(ws + 208666624);            //   2,097,152
  float*          dAv  = (float*)(ws + 210763776);            //   2,097,152  -> end 212,860,928
  // bf16 GEMM operand staging for gemm1 (xh region live only after conv):
  unsigned short* xbf = xh;                                        // [8192,2048] bf16, 33.5 MB
  unsigned short* w1b = (unsigned short*)((char*)xh + 33554432);   // [8448,2048] bf16, 34.6 MB (1MB spill into Bmp — written later by conv)
  // scan chunk-state buffers (xbc region dead after conv):
  float*          hend   = (float*)xbc;                            // [256][16][4096] f32 = 67,108,864 -> ends ws+134,217,728
  float*          chunkA = (float*)(ws + 134217728);               // [4096] f32, 16 KB -> ends ws+134,234,112
  float*          Wcp    = (float*)(ws + 134234112);               // [4][4096] f32, 64 KB (xbc-region slack) -> ends ws+134,299,648 < 137,363,456

  // 0. bf16 operand conversion for gemm1
  f32_to_bf16_kernel<<<16384, 256, 0, stream>>>(x, xbf, 4194304);          // 8192*2048/4
  convert_w1_kernel<<<16896, 256, 0, stream>>>(in_proj_w, w1b);            // 8448*512 quads

  // 1. fp32 dt path (reads fp32 x and in_proj_w directly)
  dt_kernel<<<512, 256, 0, stream>>>(x, in_proj_w, dt_bias, A_log, dtv, dAv);

  // 2. in-projection GEMM (bf16 MFMA), split output: z -> zbuf, xBC+dt -> xbc
  gemm_mfma<true, true><<<dim3(NPAD1 / 128, MROWS / 128), 256, 0, stream>>>(
      xbf, w1b, zbuf, xbc, MROWS, DINPROJ, DMODEL, DINNER, XBCCOLS);

  // 3. conv + silu (vectorized; overwrites xbf/w1b — dead after gemm1)
  conv_kernel<<<MROWS, 256, 0, stream>>>(xbc, conv_w, conv_b, xh, Bmp, Cmp);

  // 3b. Wc = cls_w @ out_proj_w (xbc-region slack; xbc contents dead after conv)
  wc_kernel<<<16, 256, 0, stream>>>(out_proj_w, cls_w, Wcp);

  // 4. chunked selective scan (y in-place over xh; hend in dead xbc region)
  scan_state_kernel<<<256 * NCHUNK, 256, 0, stream>>>(xh, Bmp, dtv, dAv, hend, chunkA);
  scan_prop_kernel<<<256, 256, 0, stream>>>(hend, chunkA);
  scan_apply_kernel<<<256 * NCHUNK, 256, 0, stream>>>(xh, Bmp, Cmp, dtv, dAv, Dv, hend, xh);

  // 5. fused gated RMSNorm + out-proj + classifier -> fp32 out
  normcls_kernel<<<MROWS, 256, 0, stream>>>(xh, zbuf, norm_w, Wcp, cls_b, (float*)d_out);
}

// Round 4
// 1348.280 us; speedup vs baseline: 5.2980x; 1.1485x over previous
//
#include <hip/hip_runtime.h>

#define BB 4
#define LL 2048
#define DMODEL 2048
#define DSTATE 64
#define DCONV 4
#define DINNER 4096
#define NHEADS 64
#define CONVDIM 4224   // DINNER + 2*DSTATE
#define DINPROJ 8384   // 2*DINNER + 2*DSTATE + NHEADS
#define NPAD1   8448   // DINPROJ padded to multiple of 256 for MFMA tiles
#define MROWS 8192     // BB*LL
#define DTROW0 8320    // 2*DINNER + 2*DSTATE : first dt row of in_proj_w
#define XBCCOLS 4288   // CONVDIM + NHEADS (cols 4096..8383 of zxbcdt)

typedef short bf16x8 __attribute__((ext_vector_type(8)));   // 8 bf16 (4 VGPRs)
typedef short bf16x4 __attribute__((ext_vector_type(4)));   // 4 bf16 (2 VGPRs)
typedef float f32x4  __attribute__((ext_vector_type(4)));   // MFMA accumulator
typedef __attribute__((address_space(1))) void as1_void;
typedef __attribute__((address_space(3))) void as3_void;

__device__ inline unsigned short f2bf(float f) {
  unsigned int u = __float_as_uint(f);
  u += 0x7FFF + ((u >> 16) & 1);   // RNE
  return (unsigned short)(u >> 16);
}
__device__ inline float bf2f(unsigned short u) {
  return __uint_as_float(((unsigned int)u) << 16);
}

// in_proj_w [8384][2048] fp32 -> bf16 padded to [8448][2048] (pad rows = 0)
__global__ void convert_w1_kernel(const float* __restrict__ w,
                                  unsigned short* __restrict__ out) {
  long q = (long)blockIdx.x * 256 + threadIdx.x;   // quad index over [8448][2048]
  long row = q >> 9;                               // 512 quads per row
  ushort4 o; o.x = 0; o.y = 0; o.z = 0; o.w = 0;
  if (row < DINPROJ) {
    float4 v = ((const float4*)w)[q];
    o.x = f2bf(v.x); o.y = f2bf(v.y); o.z = f2bf(v.z); o.w = f2bf(v.w);
  }
  ((ushort4*)out)[q] = o;
}

// ---------------- bf16 MFMA GEMM: C[M,N] = A[M,K] * B[N,K]^T ----------------
// 256x256 tile, BK=64, 8 waves (2Mx4N, each owns 128x64), double-buffered LDS
// (2 x 64KB) with 2-tile-deep prefetch and counted s_waitcnt vmcnt(8) (T4 —
// never drain to 0 mid-loop; raw s_barrier + sched_barrier fences per guide
// rule #18). Fragment layout, (row&7)<<4 XOR swizzle (both-sides: pre-swizzled
// global source + swizzled ds_read; LDS write linear) and MFMA shape identical
// to the round-1-verified 128^2 kernel. M % 256 == 0, K % 64 == 0 and K/64 >= 2,
// B padded to gridDim.x*256 rows; C stores guarded by n < N.
// SPLIT: col n < Nsplit -> Cv (ld=Nsplit), else Cv2 (ld=ld2, col n-Nsplit).
template <bool BF16OUT, bool SPLIT>
__global__ __launch_bounds__(512, 2) void gemm_mfma256(
    const unsigned short* __restrict__ A,   // bf16 [M][K]
    const unsigned short* __restrict__ B,   // bf16 [Npad][K]
    void* __restrict__ Cv, void* __restrict__ Cv2,
    int M, int N, int K, int Nsplit, int ld2) {
  __shared__ __align__(16) char lds[131072];   // buf b: A at b*65536, B at +32768
  const int tid  = threadIdx.x;
  const int lane = tid & 63;
  const int wave = tid >> 6;
  // XCD-aware bijective swizzle (requires nwg % 8 == 0; guarded).
  const int nwg = gridDim.x * gridDim.y;
  int lin = blockIdx.y * gridDim.x + blockIdx.x;
  if ((nwg & 7) == 0) { const int q = nwg >> 3; lin = (lin & 7) * q + (lin >> 3); }
  const long m0 = (long)(lin / gridDim.x) * 256;
  const long n0 = (long)(lin % gridDim.x) * 256;
  const int wm = wave >> 2;          // 0..1  -> rows wm*128..+127
  const int wn = wave & 3;           // 0..3  -> cols wn*64..+63
  const int fr = lane & 15;          // fragment row
  const int kb = lane >> 4;          // k-block 0..3 (16B each)
  const int xr = (fr & 7) << 4;      // read-side XOR (rows used are 16-aligned)
  const size_t sb = (size_t)K * 2;   // global row stride (bytes)

  f32x4 acc[8][4] = {};              // 128 VGPRs

  const int NT = K / 64;

  auto stage = [&](int kt, int b) {  // 8 x global_load_lds(16B) per thread
#pragma unroll
    for (int u = 0; u < 8; ++u) {
      const int idx  = u * 512 + tid;         // 16B slot 0..4095
      const int half = idx >> 11;             // 0 = A-tile, 1 = B-tile
      const int r    = (idx & 2047) >> 3;     // row 0..255
      const int csrc = ((idx & 7) << 4) ^ ((r & 7) << 4);  // pre-swizzled src col
      const char* g = half
          ? (const char*)B + (size_t)(n0 + r) * sb + (size_t)kt * 128 + csrc
          : (const char*)A + (size_t)(m0 + r) * sb + (size_t)kt * 128 + csrc;
      __builtin_amdgcn_global_load_lds((as1_void*)g,
          (as3_void*)(lds + b * 65536 + half * 32768 + (idx & 2047) * 16), 16, 0, 0);
    }
  };

  stage(0, 0);
  stage(1, 1);                       // 16 loads/wave in flight

  for (int kt = 0; kt < NT; ++kt) {
    const int b = kt & 1;
    // tile kt's 8 loads are the oldest; only kt+1's 8 may still be in flight.
    if (kt + 1 < NT) asm volatile("s_waitcnt vmcnt(8)" ::: "memory");
    else             asm volatile("s_waitcnt vmcnt(0)" ::: "memory");
    __builtin_amdgcn_s_barrier();
    __builtin_amdgcn_sched_barrier(0);
    const char* la = lds + b * 65536;
    const char* lb = la + 32768;
#pragma unroll
    for (int ks = 0; ks < 2; ++ks) {
      const int cread = (ks * 64 + kb * 16) ^ xr;
      bf16x8 bg[4];
#pragma unroll
      for (int nf = 0; nf < 4; ++nf)
        bg[nf] = *(const bf16x8*)(lb + (wn * 64 + nf * 16 + fr) * 128 + cread);
#pragma unroll
      for (int mf = 0; mf < 8; ++mf) {
        bf16x8 af = *(const bf16x8*)(la + (wm * 128 + mf * 16 + fr) * 128 + cread);
#pragma unroll
        for (int nf = 0; nf < 4; ++nf)
          acc[mf][nf] = __builtin_amdgcn_mfma_f32_16x16x32_bf16(af, bg[nf], acc[mf][nf], 0, 0, 0);
      }
    }
    // all ds_reads were consumed by MFMAs (lgkm drained) -> safe to re-stage
    // buf b after this barrier; loads land asynchronously, gated by vmcnt above.
    __builtin_amdgcn_sched_barrier(0);
    asm volatile("" ::: "memory");
    __builtin_amdgcn_s_barrier();
    __builtin_amdgcn_sched_barrier(0);
    if (kt + 2 < NT) stage(kt + 2, b);
  }

  // epilogue: C/D layout col = lane&15, row = (lane>>4)*4 + reg  [verified m89/m91]
#pragma unroll
  for (int mf = 0; mf < 8; ++mf) {
    const long mbase = m0 + wm * 128 + mf * 16 + kb * 4;
#pragma unroll
    for (int nf = 0; nf < 4; ++nf) {
      const long n = n0 + wn * 64 + nf * 16 + fr;
      if (n < N) {
#pragma unroll
        for (int r = 0; r < 4; ++r) {
          const long m = mbase + r;
          if (!SPLIT || n < Nsplit) {
            const long ld = SPLIT ? Nsplit : N;
            if (BF16OUT) ((unsigned short*)Cv)[m * ld + n] = f2bf(acc[mf][nf][r]);
            else         ((float*)Cv)[m * ld + n] = acc[mf][nf][r];
          } else {
            if (BF16OUT) ((unsigned short*)Cv2)[m * (long)ld2 + (n - Nsplit)] = f2bf(acc[mf][nf][r]);
            else         ((float*)Cv2)[m * (long)ld2 + (n - Nsplit)] = acc[mf][nf][r];
          }
        }
      }
    }
  }
}

// ---------------- fp32 dt path: dt_raw = x @ w_dt^T, softplus, dA ----------------
// Also emits xbf (bf16 copy of x) from the staged tiles — frees the standalone
// x->bf16 convert kernel and its extra 100 MB round-trip.
__global__ void dt_kernel(const float* __restrict__ x,
                          const float* __restrict__ w,     // in_proj_w (full)
                          const float* __restrict__ dt_bias,
                          const float* __restrict__ A_log,
                          float* __restrict__ dtv, float* __restrict__ dAv,
                          unsigned short* __restrict__ xbf) {
  __shared__ float s_w[64][129];
  __shared__ float s_x[16][129];
  const int tid = threadIdx.x;
  const int row0 = blockIdx.x * 16;
  const int c = tid & 63;        // head
  const int rg = tid >> 6;       // 0..3 -> rows rg*4..rg*4+3
  float acc[4] = {0.f, 0.f, 0.f, 0.f};
  for (int k0 = 0; k0 < DMODEL; k0 += 128) {
    __syncthreads();
#pragma unroll
    for (int u = 0; u < 32; ++u) {   // 64*128/256
      int idx = u * 256 + tid;
      int r = idx >> 7, kk = idx & 127;
      s_w[r][kk] = w[(size_t)(DTROW0 + r) * DMODEL + k0 + kk];
    }
#pragma unroll
    for (int u = 0; u < 8; ++u) {    // 16*128/256
      int idx = u * 256 + tid;
      int r = idx >> 7, kk = idx & 127;
      float v = x[(size_t)(row0 + r) * DMODEL + k0 + kk];
      s_x[r][kk] = v;
      xbf[(size_t)(row0 + r) * DMODEL + k0 + kk] = f2bf(v);
    }
    __syncthreads();
    for (int kk = 0; kk < 128; ++kk) {
      float wv = s_w[c][kk];
#pragma unroll
      for (int j = 0; j < 4; ++j) acc[j] += s_x[rg * 4 + j][kk] * wv;
    }
  }
  const float a = expf(A_log[c]);
  const float bias = dt_bias[c];
#pragma unroll
  for (int j = 0; j < 4; ++j) {
    int row = row0 + rg * 4 + j;
    float v = acc[j] + bias;
    float dt = (v > 20.f) ? v : log1pf(expf(v));   // softplus
    dtv[(size_t)row * 64 + c] = dt;
    dAv[(size_t)row * 64 + c] = expf(-dt * a);
  }
}

// ---------------- conv(4) + silu, vectorized (short8 per group) ----------------
// 528 groups of 8 channels; thread t handles groups {t, t+256, 512+t if t<16}.
__global__ void conv_kernel(const unsigned short* __restrict__ xbc,
                            const float* __restrict__ conv_w,
                            const float* __restrict__ conv_b,
                            unsigned short* __restrict__ xh,
                            float* __restrict__ Bm,
                            float* __restrict__ Cm) {
  const int row = blockIdx.x;          // b*LL + l
  const int l = row & (LL - 1);
  const int tid = threadIdx.x;
  for (int gsel = 0; gsel < 3; ++gsel) {
    int g;
    if (gsel == 0) g = tid;
    else if (gsel == 1) g = tid + 256;
    else { if (tid >= 16) break; g = 512 + tid; }
    const int c0 = g * 8;
    float cwa[8][4];
#pragma unroll
    for (int i = 0; i < 8; ++i) {
      float4 cw = *(const float4*)&conv_w[(c0 + i) * 4];
      cwa[i][0] = cw.x; cwa[i][1] = cw.y; cwa[i][2] = cw.z; cwa[i][3] = cw.w;
    }
    float acc[8];
    {
      float4 cb0 = *(const float4*)&conv_b[c0];
      float4 cb1 = *(const float4*)&conv_b[c0 + 4];
      acc[0] = cb0.x; acc[1] = cb0.y; acc[2] = cb0.z; acc[3] = cb0.w;
      acc[4] = cb1.x; acc[5] = cb1.y; acc[6] = cb1.z; acc[7] = cb1.w;
    }
#pragma unroll
    for (int k = 0; k < DCONV; ++k) {
      const int ll = l - (DCONV - 1) + k;
      if (ll >= 0) {   // wave-uniform (l uniform per block)
        const size_t rr = (size_t)(row - (DCONV - 1) + k);
        bf16x8 v = *(const bf16x8*)&xbc[rr * XBCCOLS + c0];
#pragma unroll
        for (int i = 0; i < 8; ++i)
          acc[i] += bf2f((unsigned short)v[i]) * cwa[i][k];
      }
    }
    float s[8];
#pragma unroll
    for (int i = 0; i < 8; ++i) s[i] = acc[i] / (1.f + expf(-acc[i]));
    if (g < 512) {
      bf16x8 o;
#pragma unroll
      for (int i = 0; i < 8; ++i) o[i] = (short)f2bf(s[i]);
      *(bf16x8*)&xh[(size_t)row * DINNER + c0] = o;
    } else {
      float4 o0, o1;
      o0.x = s[0]; o0.y = s[1]; o0.z = s[2]; o0.w = s[3];
      o1.x = s[4]; o1.y = s[5]; o1.z = s[6]; o1.w = s[7];
      if (g < 520) {
        float* p = &Bm[(size_t)row * DSTATE + (c0 - DINNER)];
        ((float4*)p)[0] = o0; ((float4*)p)[1] = o1;
      } else {
        float* p = &Cm[(size_t)row * DSTATE + (c0 - DINNER - DSTATE)];
        ((float4*)p)[0] = o0; ((float4*)p)[1] = o1;
      }
    }
  }
}

// ---------------- chunked selective scan ----------------
#define CT 16
#define CHUNK 128
#define NCHUNK 16   // LL / CHUNK

// Pass A1: per-(b,h,chunk) local state scan from h=0 -> hend + chunk decay prod.
__global__ void scan_state_kernel(const unsigned short* __restrict__ xhp,
                                  const float* __restrict__ Bm,
                                  const float* __restrict__ dtv,
                                  const float* __restrict__ dAv,
                                  float* __restrict__ hend,
                                  float* __restrict__ chunkA) {
  __shared__ __align__(16) float s_x[CT][64];
  __shared__ __align__(16) float s_B[CT][64];
  __shared__ float s_dt[CT], s_dA[CT];
  const int chunk = blockIdx.x & (NCHUNK - 1);
  const int bh = blockIdx.x >> 4;
  const int head = bh & 63;
  const int b = bh >> 6;
  const int tid = threadIdx.x;
  const int p = tid >> 2, q = tid & 3, n0 = q * 16;
  const int stt = tid >> 4, scc = (tid & 15) * 4;   // vectorized staging coords
  float h[16];
#pragma unroll
  for (int i = 0; i < 16; ++i) h[i] = 0.f;
  float pA = 1.f;
  const int tbase = b * LL + chunk * CHUNK;

  for (int t0 = 0; t0 < CHUNK; t0 += CT) {
    __syncthreads();
    {
      size_t r = (size_t)(tbase + t0 + stt);
      bf16x4 xv = *(const bf16x4*)&xhp[r * DINNER + head * 64 + scc];
      float4 xf;
      xf.x = bf2f((unsigned short)xv[0]); xf.y = bf2f((unsigned short)xv[1]);
      xf.z = bf2f((unsigned short)xv[2]); xf.w = bf2f((unsigned short)xv[3]);
      *(float4*)&s_x[stt][scc] = xf;
      *(float4*)&s_B[stt][scc] = *(const float4*)&Bm[r * 64 + scc];
    }
    if (tid < CT) {
      size_t r = (size_t)(tbase + t0 + tid);
      s_dt[tid] = dtv[r * 64 + head];
      s_dA[tid] = dAv[r * 64 + head];
    }
    __syncthreads();
    for (int tt = 0; tt < CT; ++tt) {
      float dA = s_dA[tt];
      float dtx = s_dt[tt] * s_x[tt][p];
      pA *= dA;
      const float4* Bp = (const float4*)&s_B[tt][n0];
#pragma unroll
      for (int i = 0; i < 4; ++i) {
        float4 bv = Bp[i];
        h[4*i+0] = h[4*i+0] * dA + dtx * bv.x;
        h[4*i+1] = h[4*i+1] * dA + dtx * bv.y;
        h[4*i+2] = h[4*i+2] * dA + dtx * bv.z;
        h[4*i+3] = h[4*i+3] * dA + dtx * bv.w;
      }
    }
  }
  float* hp = hend + ((size_t)bh * NCHUNK + chunk) * 4096 + tid * 16;
#pragma unroll
  for (int i = 0; i < 4; ++i) {
    float4 v; v.x = h[4*i]; v.y = h[4*i+1]; v.z = h[4*i+2]; v.w = h[4*i+3];
    ((float4*)hp)[i] = v;
  }
  if (tid == 0) chunkA[bh * NCHUNK + chunk] = pA;
}

// Pass B: in-place inter-chunk propagation: slot c := h_start(chunk c).
__global__ void scan_prop_kernel(float* __restrict__ hend,
                                 const float* __restrict__ chunkA) {
  const int bh = blockIdx.x;     // 256
  const int tid = threadIdx.x;   // 256
  float cr[16];
#pragma unroll
  for (int i = 0; i < 16; ++i) cr[i] = 0.f;
  for (int c = 0; c < NCHUNK; ++c) {
    float* hp = hend + ((size_t)bh * NCHUNK + c) * 4096 + tid * 16;
    const float a = chunkA[bh * NCHUNK + c];
    float e[16];
#pragma unroll
    for (int i = 0; i < 4; ++i) {
      float4 v = ((float4*)hp)[i];
      e[4*i] = v.x; e[4*i+1] = v.y; e[4*i+2] = v.z; e[4*i+3] = v.w;
    }
#pragma unroll
    for (int i = 0; i < 4; ++i) {
      float4 v; v.x = cr[4*i]; v.y = cr[4*i+1]; v.z = cr[4*i+2]; v.w = cr[4*i+3];
      ((float4*)hp)[i] = v;
    }
#pragma unroll
    for (int i = 0; i < 16; ++i) cr[i] = cr[i] * a + e[i];
  }
}

// Pass A2: full scan per chunk from h_start, writing y (in-place over xh).
__global__ void scan_apply_kernel(const unsigned short* xhp,   // NOT restrict: y aliases
                                  const float* __restrict__ Bm,
                                  const float* __restrict__ Cm,
                                  const float* __restrict__ dtv,
                                  const float* __restrict__ dAv,
                                  const float* __restrict__ Dv,
                                  const float* __restrict__ hstart,
                                  unsigned short* y) {
  __shared__ __align__(16) float s_x[CT][64];
  __shared__ __align__(16) float s_B[CT][64];
  __shared__ __align__(16) float s_C[CT][64];
  __shared__ __align__(16) float s_y[CT][64];
  __shared__ float s_dt[CT], s_dA[CT];
  const int chunk = blockIdx.x & (NCHUNK - 1);
  const int bh = blockIdx.x >> 4;
  const int head = bh & 63;
  const int b = bh >> 6;
  const int tid = threadIdx.x;
  const int p = tid >> 2, q = tid & 3, n0 = q * 16;
  const int stt = tid >> 4, scc = (tid & 15) * 4;
  const float Dh = Dv[head];
  const int tbase = b * LL + chunk * CHUNK;

  float h[16];
  {
    const float* hp = hstart + ((size_t)bh * NCHUNK + chunk) * 4096 + tid * 16;
#pragma unroll
    for (int i = 0; i < 4; ++i) {
      float4 v = ((const float4*)hp)[i];
      h[4*i] = v.x; h[4*i+1] = v.y; h[4*i+2] = v.z; h[4*i+3] = v.w;
    }
  }

  for (int t0 = 0; t0 < CHUNK; t0 += CT) {
    __syncthreads();   // previous sub-chunk's s_y reads done before overwrite
    {
      size_t r = (size_t)(tbase + t0 + stt);
      bf16x4 xv = *(const bf16x4*)&xhp[r * DINNER + head * 64 + scc];
      float4 xf;
      xf.x = bf2f((unsigned short)xv[0]); xf.y = bf2f((unsigned short)xv[1]);
      xf.z = bf2f((unsigned short)xv[2]); xf.w = bf2f((unsigned short)xv[3]);
      *(float4*)&s_x[stt][scc] = xf;
      *(float4*)&s_B[stt][scc] = *(const float4*)&Bm[r * 64 + scc];
      *(float4*)&s_C[stt][scc] = *(const float4*)&Cm[r * 64 + scc];
    }
    if (tid < CT) {
      size_t r = (size_t)(tbase + t0 + tid);
      s_dt[tid] = dtv[r * 64 + head];
      s_dA[tid] = dAv[r * 64 + head];
    }
    __syncthreads();
    for (int tt = 0; tt < CT; ++tt) {
      float dA = s_dA[tt], dt = s_dt[tt];
      float xp = s_x[tt][p];
      float dtx = dt * xp;
      const float4* Bp = (const float4*)&s_B[tt][n0];
      const float4* Cp = (const float4*)&s_C[tt][n0];
      float ys = 0.f;
#pragma unroll
      for (int i = 0; i < 4; ++i) {
        float4 bv = Bp[i];
        float4 cv = Cp[i];
        h[4*i+0] = h[4*i+0] * dA + dtx * bv.x;  ys += h[4*i+0] * cv.x;
        h[4*i+1] = h[4*i+1] * dA + dtx * bv.y;  ys += h[4*i+1] * cv.y;
        h[4*i+2] = h[4*i+2] * dA + dtx * bv.z;  ys += h[4*i+2] * cv.z;
        h[4*i+3] = h[4*i+3] * dA + dtx * bv.w;  ys += h[4*i+3] * cv.w;
      }
      ys += __shfl_xor(ys, 1);
      ys += __shfl_xor(ys, 2);
      if (q == 0) s_y[tt][p] = ys + Dh * xp;
    }
    __syncthreads();   // all waves' s_y writes visible before cross-wave reads
    {
      size_t r = (size_t)(tbase + t0 + stt);
      float4 yv = *(const float4*)&s_y[stt][scc];
      bf16x4 o;
      o[0] = (short)f2bf(yv.x); o[1] = (short)f2bf(yv.y);
      o[2] = (short)f2bf(yv.z); o[3] = (short)f2bf(yv.w);
      *(bf16x4*)&y[r * DINNER + head * 64 + scc] = o;
    }
  }
}

// ---------------- Wc = cls_w @ out_proj_w : [4][4096] fp32, 2-stage ----------------
// Stage 1: grid (16 e-tiles x 16 d-chunks) = 256 blocks, coalesced W reads.
__global__ void wc_part_kernel(const float* __restrict__ W,    // out_proj_w [2048][4096]
                               const float* __restrict__ C,    // cls_w [4][2048]
                               float* __restrict__ part) {     // [16][4][4096]
  const int e = blockIdx.x * 256 + threadIdx.x;
  const int d0 = blockIdx.y * 128;
  float a0 = 0, a1 = 0, a2 = 0, a3 = 0;
  for (int d = d0; d < d0 + 128; ++d) {
    float wv = W[(size_t)d * DINNER + e];
    a0 += C[d] * wv;
    a1 += C[DMODEL + d] * wv;
    a2 += C[2 * DMODEL + d] * wv;
    a3 += C[3 * DMODEL + d] * wv;
  }
  float* pp = part + (size_t)blockIdx.y * 4 * DINNER;
  pp[e] = a0; pp[DINNER + e] = a1; pp[2 * DINNER + e] = a2; pp[3 * DINNER + e] = a3;
}
// Stage 2: reduce 16 partials.
__global__ void wc_reduce_kernel(const float* __restrict__ part,
                                 float* __restrict__ Wc) {
  const int i = blockIdx.x * 256 + threadIdx.x;   // 0..16383
  float s = 0.f;
#pragma unroll
  for (int p = 0; p < 16; ++p) s += part[(size_t)p * 4 * DINNER + i];
  Wc[i] = s;
}

// ---------------- fused gated RMSNorm + classifier projection ----------------
// out[row][c] = sum_d ( y*silu(z)*rs*norm_w )[d] * Wc[c][d] + cls_b[c]
__global__ void normcls_kernel(const unsigned short* __restrict__ y,
                               const unsigned short* __restrict__ z,
                               const float* __restrict__ norm_w,
                               const float* __restrict__ Wc,
                               const float* __restrict__ cls_b,
                               float* __restrict__ out) {
  const int row = blockIdx.x;
  const int tid = threadIdx.x;
  const int d0 = tid * 16;
  const size_t base = (size_t)row * DINNER + d0;
  bf16x8 yv0 = *(const bf16x8*)&y[base];
  bf16x8 yv1 = *(const bf16x8*)&y[base + 8];
  bf16x8 zv0 = *(const bf16x8*)&z[base];
  bf16x8 zv1 = *(const bf16x8*)&z[base + 8];
  float g[16];
  float ss = 0.f;
#pragma unroll
  for (int i = 0; i < 8; ++i) {
    float zz = bf2f((unsigned short)zv0[i]);
    float gv = bf2f((unsigned short)yv0[i]) * (zz / (1.f + expf(-zz)));
    g[i] = gv; ss += gv * gv;
  }
#pragma unroll
  for (int i = 0; i < 8; ++i) {
    float zz = bf2f((unsigned short)zv1[i]);
    float gv = bf2f((unsigned short)yv1[i]) * (zz / (1.f + expf(-zz)));
    g[8 + i] = gv; ss += gv * gv;
  }
#pragma unroll
  for (int off = 32; off >= 1; off >>= 1) ss += __shfl_xor(ss, off);
  __shared__ float sred[4];
  __shared__ float s_rs;
  if ((tid & 63) == 0) sred[tid >> 6] = ss;
  __syncthreads();
  if (tid == 0)
    s_rs = rsqrtf((sred[0] + sred[1] + sred[2] + sred[3]) / (float)DINNER + 1e-5f);
  __syncthreads();
  const float rs = s_rs;
  float gn[16];
#pragma unroll
  for (int j = 0; j < 4; ++j) {
    float4 nw = *(const float4*)&norm_w[d0 + j * 4];
    gn[j*4+0] = g[j*4+0] * rs * nw.x;
    gn[j*4+1] = g[j*4+1] * rs * nw.y;
    gn[j*4+2] = g[j*4+2] * rs * nw.z;
    gn[j*4+3] = g[j*4+3] * rs * nw.w;
  }
  float a[4] = {0.f, 0.f, 0.f, 0.f};
#pragma unroll
  for (int c = 0; c < 4; ++c) {
#pragma unroll
    for (int j = 0; j < 4; ++j) {
      float4 w4 = *(const float4*)&Wc[c * DINNER + d0 + j * 4];
      a[c] += gn[j*4+0]*w4.x + gn[j*4+1]*w4.y + gn[j*4+2]*w4.z + gn[j*4+3]*w4.w;
    }
  }
#pragma unroll
  for (int off = 32; off >= 1; off >>= 1) {
#pragma unroll
    for (int c = 0; c < 4; ++c) a[c] += __shfl_xor(a[c], off);
  }
  __shared__ float s4[4][4];
  if ((tid & 63) == 0) {
    int w = tid >> 6;
    s4[w][0] = a[0]; s4[w][1] = a[1]; s4[w][2] = a[2]; s4[w][3] = a[3];
  }
  __syncthreads();
  if (tid < 4)
    out[(size_t)row * 4 + tid] = s4[0][tid] + s4[1][tid] + s4[2][tid] + s4[3][tid] + cls_b[tid];
}

extern "C" void kernel_launch(void* const* d_in, const int* in_sizes, int n_in,
                              void* d_out, int out_size, void* d_ws, size_t ws_size,
                              hipStream_t stream) {
  const float* x          = (const float*)d_in[0];
  const float* in_proj_w  = (const float*)d_in[1];
  const float* conv_w     = (const float*)d_in[2];
  const float* conv_b     = (const float*)d_in[3];
  const float* dt_bias    = (const float*)d_in[4];
  const float* A_log      = (const float*)d_in[5];
  const float* Dv         = (const float*)d_in[6];
  const float* norm_w     = (const float*)d_in[7];
  const float* out_proj_w = (const float*)d_in[8];
  const float* cls_w      = (const float*)d_in[9];
  const float* cls_b      = (const float*)d_in[10];

  char* ws = (char*)d_ws;
  // workspace layout (total 212,860,928 bytes):
  unsigned short* zbuf = (unsigned short*)(ws + 0);           //  67,108,864  bf16 [8192,4096]  z cols
  unsigned short* xbc  = (unsigned short*)(ws + 67108864);    //  70,254,592  bf16 [8192,4288]  xBC+dt cols
  unsigned short* xh   = (unsigned short*)(ws + 137363456);   //  67,108,864  bf16 [8192,4096]
  float*          Bmp  = (float*)(ws + 204472320);            //   2,097,152
  float*          Cmp  = (float*)(ws + 206569472);            //   2,097,152
  float*          dtv  = (float*)(ws + 208666624);            //   2,097,152
  float*          dAv  = (float*)(ws + 210763776);            //   2,097,152  -> end 212,860,928
  // bf16 GEMM operand staging for gemm1 (xh region live only after conv):
  unsigned short* xbf = xh;                                        // [8192,2048] bf16, 33.5 MB
  unsigned short* w1b = (unsigned short*)((char*)xh + 33554432);   // [8448,2048] bf16, 34.6 MB (1MB spill into Bmp — written later by conv)
  // dead-xbc-region buffers (xbc contents dead after conv):
  float*          hend   = (float*)xbc;                            // [256][16][4096] f32 -> ends ws+134,217,728
  float*          chunkA = (float*)(ws + 134217728);               // 16 KB -> ends ws+134,234,112
  float*          Wcp    = (float*)(ws + 134234112);               // [4][4096] f32, 64 KB -> ends ws+134,299,648
  float*          wcpart = (float*)(ws + 134299648);               // [16][4][4096] f32, 1 MB -> ends ws+135,348,224 < 137,363,456

  // 1. fp32 dt path; also emits xbf (bf16 x) for gemm1
  dt_kernel<<<512, 256, 0, stream>>>(x, in_proj_w, dt_bias, A_log, dtv, dAv, xbf);

  // 1b. in_proj_w -> bf16 padded
  convert_w1_kernel<<<16896, 256, 0, stream>>>(in_proj_w, w1b);            // 8448*512 quads

  // 2. in-projection GEMM (bf16 MFMA 256^2, counted-vmcnt double-buffer),
  //    split output: z -> zbuf, xBC+dt -> xbc
  gemm_mfma256<true, true><<<dim3(NPAD1 / 256, MROWS / 256), 512, 0, stream>>>(
      xbf, w1b, zbuf, xbc, MROWS, DINPROJ, DMODEL, DINNER, XBCCOLS);

  // 3. conv + silu (overwrites xbf/w1b — dead after gemm1)
  conv_kernel<<<MROWS, 256, 0, stream>>>(xbc, conv_w, conv_b, xh, Bmp, Cmp);

  // 3b. Wc = cls_w @ out_proj_w (2-stage; buffers in dead-xbc slack)
  wc_part_kernel<<<dim3(16, 16), 256, 0, stream>>>(out_proj_w, cls_w, wcpart);
  wc_reduce_kernel<<<64, 256, 0, stream>>>(wcpart, Wcp);

  // 4. chunked selective scan (y in-place over xh; hend in dead xbc region)
  scan_state_kernel<<<256 * NCHUNK, 256, 0, stream>>>(xh, Bmp, dtv, dAv, hend, chunkA);
  scan_prop_kernel<<<256, 256, 0, stream>>>(hend, chunkA);
  scan_apply_kernel<<<256 * NCHUNK, 256, 0, stream>>>(xh, Bmp, Cmp, dtv, dAv, Dv, hend, xh);

  // 5. fused gated RMSNorm + out-proj + classifier -> fp32 out
  normcls_kernel<<<MROWS, 256, 0, stream>>>(xh, zbuf, norm_w, Wcp, cls_b, (float*)d_out);
}